// Round 2
// baseline (1909.735 us; speedup 1.0000x reference)
//
#include <hip/hip_runtime.h>
#include <hip/hip_bf16.h>
#include <math.h>

using bf16 = __hip_bfloat16;
typedef __attribute__((ext_vector_type(4))) float f32x4;
typedef __attribute__((ext_vector_type(8))) short short8;

#define B_N 32
#define S_N 512
#define T_N 50
#define H_N 8
#define NL_N 4
#define VB_N 30000
#define VBP_N 30016          // VB padded to mult of 64
#define ST_N 562
#define STP_N 576
#define NTOK_N (B_N*ST_N)   // 17984
#define WCH_N 16             // softmax_wdec column chunks
#define WCW_N 1875           // 30000/16

__device__ __forceinline__ float b2f(bf16 x){ return __bfloat162float(x); }
__device__ __forceinline__ bf16  f2b(float x){ return __float2bfloat16(x); }
// flag-aware raw-input load: f==1 -> buffer is float32, else bf16
__device__ __forceinline__ float ldw(const void* p, long i, int f){
    return f ? ((const float*)p)[i] : __bfloat162float(((const bf16*)p)[i]);
}

__device__ __forceinline__ void load_lds16(const void* g, void* l){
    __builtin_amdgcn_global_load_lds((const __attribute__((address_space(1))) void*)g,
                                     (__attribute__((address_space(3))) void*)l, 16, 0, 0);
}

__device__ __forceinline__ float block_reduce_max(float v, float* red, int t){
    for (int o=32;o>0;o>>=1) v = fmaxf(v, __shfl_down(v,o,64));
    int w=t>>6, lane=t&63;
    if (lane==0) red[w]=v;
    __syncthreads();
    return fmaxf(fmaxf(red[0],red[1]),fmaxf(red[2],red[3]));
}
__device__ __forceinline__ float block_reduce_sum(float v, float* red, int t){
    for (int o=32;o>0;o>>=1) v += __shfl_down(v,o,64);
    int w=t>>6, lane=t&63;
    if (lane==0) red[w]=v;
    __syncthreads();
    return red[0]+red[1]+red[2]+red[3];
}

// ---------------- dtype detector ----------------
__global__ __launch_bounds__(256) void detect_k(const unsigned int* __restrict__ w, int* flag)
{
    int t = threadIdx.x;
    float s = 0.f;
    for (int i=t;i<4096;i+=256){ int e = (w[i]>>7)&0xFF; s += fabsf((float)e - 120.f); }
    __shared__ float red[4];
    for (int o=32;o>0;o>>=1) s += __shfl_down(s,o,64);
    int wv=t>>6, lane=t&63;
    if (lane==0) red[wv]=s;
    __syncthreads();
    if (t==0) flag[0] = ((red[0]+red[1]+red[2]+red[3]) * (1.f/4096.f) > 20.f) ? 1 : 0;
}

__global__ void zero_u32_k(unsigned int* p, long n){
    long i = (long)blockIdx.x*256 + threadIdx.x;
    if (i < n) p[i] = 0u;
}

// ---------------- topic memory: parallel W_dec softmax ----------------
__global__ __launch_bounds__(256) void wd_partmax_k(
    const void* __restrict__ Wd, const void* __restrict__ bd,
    float* __restrict__ pmax, const int* __restrict__ flagp)
{
    const int isf = *flagp;
    int ch = blockIdx.x, r = blockIdx.y, t = threadIdx.x;
    int c0 = ch*WCW_N, c1 = c0 + WCW_N;
    __shared__ float red[4];
    float mx = -1e30f;
    for (int c=c0+t;c<c1;c+=256) mx = fmaxf(mx, ldw(Wd,(long)r*VB_N+c,isf) + ldw(bd,c,isf));
    mx = block_reduce_max(mx, red, t);
    if (t==0) pmax[r*WCH_N + ch] = mx;
}

__global__ __launch_bounds__(256) void wd_partsum_k(
    const void* __restrict__ Wd, const void* __restrict__ bd,
    const float* __restrict__ pmax, float* __restrict__ psum, const int* __restrict__ flagp)
{
    const int isf = *flagp;
    int ch = blockIdx.x, r = blockIdx.y, t = threadIdx.x;
    float mx = -1e30f;
    #pragma unroll
    for (int i=0;i<WCH_N;i++) mx = fmaxf(mx, pmax[r*WCH_N+i]);
    int c0 = ch*WCW_N, c1 = c0 + WCW_N;
    __shared__ float red[4];
    float sm = 0.f;
    for (int c=c0+t;c<c1;c+=256) sm += __expf(ldw(Wd,(long)r*VB_N+c,isf) + ldw(bd,c,isf) - mx);
    sm = block_reduce_sum(sm, red, t);
    if (t==0) psum[r*WCH_N + ch] = sm;
}

__global__ __launch_bounds__(256) void wd_write_k(
    const void* __restrict__ Wd, const void* __restrict__ bd,
    const float* __restrict__ pmax, const float* __restrict__ psum,
    bf16* __restrict__ wdb, const int* __restrict__ flagp)
{
    const int isf = *flagp;
    int ch = blockIdx.x, r = blockIdx.y, t = threadIdx.x;
    float mx = -1e30f, sm = 0.f;
    #pragma unroll
    for (int i=0;i<WCH_N;i++){ mx = fmaxf(mx, pmax[r*WCH_N+i]); sm += psum[r*WCH_N+i]; }
    float inv = 1.f/sm;
    int c0 = ch*WCW_N, c1 = c0 + WCW_N;
    for (int c=c0+t;c<c1;c+=256)
        wdb[(long)r*VBP_N + c] = f2b(__expf(ldw(Wd,(long)r*VB_N+c,isf) + ldw(bd,c,isf) - mx)*inv);
}

// hrel[64][1024] bf16 = relu(hmem + b1), rows >= T_N zeroed
__global__ __launch_bounds__(256) void relu_bias_k(
    const float* __restrict__ hmem, const void* __restrict__ b1,
    bf16* __restrict__ hrel, const int* __restrict__ flagp)
{
    const int isf = *flagp;
    int r = blockIdx.x, t = threadIdx.x;
    for (int c=t;c<1024;c+=256){
        float v = (r < T_N) ? fmaxf(hmem[r*1024+c] + ldw(b1,c,isf), 0.f) : 0.f;
        hrel[r*1024+c] = f2b(v);
    }
}

// plain LN over 50 rows of fcout[64][512] (bias b2 already added in GEMM epilogue)
__global__ __launch_bounds__(256) void ln_topic_k(
    const float* __restrict__ fcout,
    const void* __restrict__ lg, const void* __restrict__ lb,
    float* __restrict__ tmf, bf16* __restrict__ tmb, const int* __restrict__ flagp)
{
    const int isf = *flagp;
    int r = blockIdx.x, t = threadIdx.x;
    float a0 = fcout[r*512+t], a1 = fcout[r*512+t+256];
    __shared__ float red[4];
    float mean = block_reduce_sum(a0+a1, red, t) * (1.f/512.f);
    float d0=a0-mean, d1=a1-mean;
    __syncthreads();
    float var = block_reduce_sum(d0*d0+d1*d1, red, t) * (1.f/512.f);
    float rstd = rsqrtf(var + 1e-12f);
    float o0 = d0*rstd*ldw(lg,t,isf) + ldw(lb,t,isf);
    float o1 = d1*rstd*ldw(lg,t+256,isf) + ldw(lb,t+256,isf);
    tmf[r*512+t]=o0; tmf[r*512+t+256]=o1;
    tmb[r*512+t]=f2b(o0); tmb[r*512+t+256]=f2b(o1);
}

// ---------------- embedding + ragged insert ----------------
__global__ __launch_bounds__(256) void embed_insert_k(
    const int* __restrict__ ids, const int* __restrict__ lens,
    const void* __restrict__ embed, const float* __restrict__ tmf,
    const bf16* __restrict__ tmb, float* __restrict__ hf, bf16* __restrict__ hb,
    const int* __restrict__ flagp)
{
    const int isf = *flagp;
    int j = blockIdx.x, b = blockIdx.y, t = threadIdx.x;
    int L = lens[b]; L = L<1?1:(L>S_N?S_N:L);
    long orow = ((long)b*ST_N + j)*512;
    if (j >= L && j < L + T_N) {
        int m = j - L;
        for (int c=t;c<512;c+=256){ float v = tmf[m*512+c]; hf[orow+c]=v; hb[orow+c]=tmb[m*512+c]; }
    } else {
        int sj = (j < L) ? j : j - T_N;   // in [0, 511]
        int id = ids[b*S_N + sj];
        for (int c=t;c<512;c+=256){ float e = ldw(embed,(long)id*512+c,isf); hf[orow+c]=e; hb[orow+c]=f2b(e); }
    }
}

// ---------------- weight prep ----------------
// dst[z*dstride + (n0+n)*R + (k0+k)] = src[z*sstride + min(k0+k,Ksrc-1)*C + (n0+n)]
__global__ __launch_bounds__(256) void transpose_k(
    const void* __restrict__ src, bf16* __restrict__ dst,
    int R, int C, long sstride, long dstride, int Ksrc, const int* __restrict__ flagp)
{
    const int isf = *flagp;
    __shared__ bf16 tile[32][33];
    int n0 = blockIdx.x * 32, k0 = blockIdx.y * 32, z = blockIdx.z;
    int t = threadIdx.x;
    int nl = t & 31, kb = t >> 5;
    #pragma unroll
    for (int i=0;i<4;i++) {
        int k = k0 + kb + i*8; k = k < Ksrc ? k : Ksrc-1;
        tile[kb+i*8][nl] = f2b(ldw(src, z*sstride + (long)k*C + n0+nl, isf));
    }
    __syncthreads();
    int kl = t & 31, nb = t >> 5;
    #pragma unroll
    for (int i=0;i<4;i++) {
        int n = nb + i*8;
        dst[z*dstride + (long)(n0+n)*R + k0+kl] = tile[kl][n];
    }
}

__global__ void concat_bias_k(const void* bq, const void* bk, const void* bv, bf16* out,
                              const int* __restrict__ flagp){
    const int isf = *flagp;
    int i = blockIdx.x*256 + threadIdx.x;
    if (i >= NL_N*1536) return;
    int l = i/1536, n = i%1536;
    float v = (n<512) ? ldw(bq,l*512+n,isf) : (n<1024 ? ldw(bk,l*512+n-512,isf) : ldw(bv,l*512+n-1024,isf));
    out[i] = f2b(v);
}

// Vt[z][n][k]: n = head dim (64), k = key (576, zero pad k>=562); z = b*8+h over all 256
// Early-exit: flash only reads k-tiles < ceil((L+T)/64), skip blocks beyond that.
__global__ __launch_bounds__(256) void transpose_v_k(
    const bf16* __restrict__ qkv, bf16* __restrict__ Vt, const int* __restrict__ slens)
{
    __shared__ bf16 tl[64*33];
    int k0 = blockIdx.x * 32, z = blockIdx.z;
    int b = z >> 3, h = z & 7;
    int L = slens[b]; L = L<1?1:(L>S_N?S_N:L);
    int kmax = ((L + T_N + 63) >> 6) << 6;   // active k region rounded to 64
    if (k0 >= kmax) return;
    int t = threadIdx.x;
    int n = t & 63, kb = t >> 6;
    #pragma unroll
    for (int i=0;i<8;i++) {
        int kl = kb + 4*i;
        int kg = k0 + kl;
        bf16 v = (kg < ST_N) ? qkv[((long)(b*ST_N + kg))*1536 + 1024 + h*64 + n] : f2b(0.f);
        tl[n*33 + kl] = v;
    }
    __syncthreads();
    int kk = t & 31, nb = t >> 5;
    #pragma unroll
    for (int i=0;i<8;i++) {
        int nn = nb + 8*i;
        Vt[((long)z*64 + nn)*STP_N + k0 + kk] = tl[nn*33 + kk];
    }
}

// ---------------- MFMA GEMM: C = A[M,K] @ Bt[N,K]^T ----------------
// BK=32 (64 B rows) double-buffered: per K-step {barrier; stage(next buf);
// ds_read cur; MFMA}. The barrier's implicit vmcnt(0) drains loads that were
// issued one full compute phase earlier -> HBM latency overlaps MFMA.
// Swizzle: LDS chunk slot s of row r holds global chunk s ^ ((r>>1)&3);
// ds_read lane footprint = 8 lanes per 16B slot over all 8 slots of the 128B
// bank span -> conflict-free. K must be mult of 32.
constexpr int EPI_BF16=0, EPI_F32=1, EPI_GELU=2, EPI_ATOMIC=3, EPI_BF16R=4;

template<int BM, int BN, int MODE>
__global__ __launch_bounds__(256,4) void gemm_k(
    const bf16* __restrict__ Ag, const bf16* __restrict__ Bg, void* __restrict__ Cg,
    const void* __restrict__ bias, long bias_off,
    int M, int N, int K, int lda, int ldb, int ldc, int Nst, int kch,
    const int* __restrict__ flagp)
{
    const int isf = *flagp;
    __shared__ __align__(16) bf16 lA[2][BM*32];
    __shared__ __align__(16) bf16 lB[2][BN*32];
    const int tid = threadIdx.x;
    const int tile_m = blockIdx.y * BM;
    const int tile_n = blockIdx.x * BN;

    bf16*  C16 = (bf16*)Cg;
    float* C32 = (float*)Cg;

    constexpr int WM = BM/2, WN = BN/2, MI = WM/16, NI = WN/16;
    const int w = tid>>6, lane = tid&63;
    const int wm = w>>1, wn = w&1;
    const int quad = lane>>4, lrow = lane&15;

    f32x4 zero = {0.f,0.f,0.f,0.f};
    f32x4 acc[MI][NI];
    #pragma unroll
    for (int i=0;i<MI;i++)
        #pragma unroll
        for (int j=0;j<NI;j++) acc[i][j] = zero;

    int ks = 0, ke = K;
    if (kch > 0) { ks = blockIdx.z * kch; ke = ks + kch; if (ke > K) ke = K; }

    auto stage = [&](int buf, int k0){
        #pragma unroll
        for (int r=0;r<BM/64;r++) {
            int e = r*256 + tid;             // [0, BM*4) 16B slots
            int row = e>>2, c4 = (e&3) ^ ((row>>1)&3);
            int gr = tile_m + row; gr = gr < M ? gr : M-1;
            load_lds16(Ag + (long)gr*lda + k0 + c4*8, &lA[buf][e*8]);
        }
        #pragma unroll
        for (int r=0;r<BN/64;r++) {
            int e = r*256 + tid;
            int row = e>>2, c4 = (e&3) ^ ((row>>1)&3);
            int gr = tile_n + row; gr = gr < N ? gr : N-1;
            load_lds16(Bg + (long)gr*ldb + k0 + c4*8, &lB[buf][e*8]);
        }
    };

    stage(0, ks);
    int cur = 0;
    for (int k0=ks;k0<ke;k0+=32) {
        __syncthreads();                       // cur-buf loads landed; prev reads done
        if (k0+32 < ke) stage(cur^1, k0+32);   // overlaps compute below
        short8 afr[MI], bfr[NI];
        #pragma unroll
        for (int i=0;i<MI;i++){
            int row = wm*WM + i*16 + lrow;
            afr[i] = *(const short8*)&lA[cur][row*32 + ((quad ^ ((row>>1)&3))<<3)];
        }
        #pragma unroll
        for (int j=0;j<NI;j++){
            int row = wn*WN + j*16 + lrow;
            bfr[j] = *(const short8*)&lB[cur][row*32 + ((quad ^ ((row>>1)&3))<<3)];
        }
        #pragma unroll
        for (int i=0;i<MI;i++)
            #pragma unroll
            for (int j=0;j<NI;j++)
                acc[i][j] = __builtin_amdgcn_mfma_f32_16x16x32_bf16(afr[i], bfr[j], acc[i][j], 0, 0, 0);
        cur ^= 1;
    }

    #pragma unroll
    for (int i=0;i<MI;i++) {
        #pragma unroll
        for (int j=0;j<NI;j++) {
            int col = tile_n + wn*WN + j*16 + lrow;
            int rb  = tile_m + wm*WM + i*16 + quad*4;
            #pragma unroll
            for (int r=0;r<4;r++) {
                int row = rb + r;
                if (row >= M || col >= Nst) continue;
                float v = acc[i][j][r];
                if constexpr (MODE == EPI_BF16) {
                    C16[(long)row*ldc + col] = f2b(v + b2f(((const bf16*)bias)[bias_off + col]));
                } else if constexpr (MODE == EPI_F32) {
                    C32[(long)row*ldc + col] = v + ldw(bias, bias_off + col, isf);
                } else if constexpr (MODE == EPI_GELU) {
                    float x = v + ldw(bias, bias_off + col, isf);
                    C16[(long)row*ldc + col] = f2b(0.5f*x*(1.f + erff(x*0.70710678118654752f)));
                } else if constexpr (MODE == EPI_BF16R) {
                    C16[(long)row*ldc + col] = f2b(v + ldw(bias, bias_off + col, isf));
                } else { // EPI_ATOMIC
                    atomicAdd(&C32[(long)row*ldc + col], v);
                }
            }
        }
    }
}

// ---------------- flash attention ----------------
// Early-exit over KV tiles (bit-identical: masked tiles give exp()==0.0f).
// K/V double-buffered: next-K staged after barrier-1 (hides under QK+softmax),
// next-V staged after barrier-2 (hides under PV). LDS 64KB = 2 blocks/CU,
// matching the launch_bounds cap, so occupancy is unchanged.
__global__ __launch_bounds__(256,2) void flash_k(
    const bf16* __restrict__ qkv, const bf16* __restrict__ Vt,
    bf16* __restrict__ ctx, const int* __restrict__ slens)
{
    __shared__ __align__(16) bf16 lQ[128*64];
    __shared__ __align__(16) bf16 lK[2][64*64];
    __shared__ __align__(16) bf16 lV[2][64*64];
    __shared__ __align__(16) bf16 lP[128*64];
    const int z = blockIdx.z, b = z>>3, h = z&7;
    const int qt = blockIdx.x;
    const int tid = threadIdx.x;
    const int w = tid>>6, lane = tid&63;
    const int quad = lane>>4, l15 = lane&15;
    int L = slens[b]; L = L<1?1:(L>S_N?S_N:L);
    const int lenT = L + T_N;
    const int nkt = (lenT + 63) >> 6;   // active KV tiles (wave-uniform)

    #pragma unroll
    for (int rr=0;rr<4;rr++){
        int ci = rr*256 + tid;
        int row = ci>>3, c8 = (ci&7) ^ (row&7);
        int gr = qt*128 + row; gr = gr < ST_N ? gr : ST_N-1;
        load_lds16(qkv + ((long)(b*ST_N+gr))*1536 + h*64 + c8*8, &lQ[ci*8]);
    }

    auto stage_K = [&](int buf, int kt){
        #pragma unroll
        for (int rr=0;rr<2;rr++){
            int ci = rr*256+tid;
            int row = ci>>3, c8 = (ci&7) ^ (row&7);
            int kr = kt*64+row; kr = kr < ST_N ? kr : ST_N-1;
            load_lds16(qkv + ((long)(b*ST_N+kr))*1536 + 512 + h*64 + c8*8, &lK[buf][ci*8]);
        }
    };
    auto stage_V = [&](int buf, int kt){
        #pragma unroll
        for (int rr=0;rr<2;rr++){
            int ci = rr*256+tid;
            int n = ci>>3, c8 = (ci&7) ^ (n&7);
            load_lds16(Vt + ((long)z*64+n)*STP_N + kt*64 + c8*8, &lV[buf][ci*8]);
        }
    };

    stage_K(0, 0);
    stage_V(0, 0);

    f32x4 zerov = {0.f,0.f,0.f,0.f};
    f32x4 O[2][4];
    float m_i[2][4], l_i[2][4];
    #pragma unroll
    for (int i=0;i<2;i++){
        #pragma unroll
        for (int j=0;j<4;j++) O[i][j] = zerov;
        #pragma unroll
        for (int r=0;r<4;r++){ m_i[i][r]=-1e30f; l_i[i][r]=0.f; }
    }

    for (int kt=0; kt<nkt; kt++){
        const int cur = kt & 1;
        __syncthreads();                         // K[cur],V[cur] ready; lP reads done
        if (kt+1 < nkt) stage_K(cur^1, kt+1);    // overlaps QK + softmax

        f32x4 S[2][4];
        #pragma unroll
        for (int i=0;i<2;i++)
            #pragma unroll
            for (int j=0;j<4;j++) S[i][j] = zerov;
        #pragma unroll
        for (int kc=0;kc<2;kc++){
            short8 aQ[2], bK[4];
            #pragma unroll
            for (int i=0;i<2;i++){
                int row = w*32+i*16+l15;
                aQ[i] = *(const short8*)&lQ[row*64 + (((kc*4+quad) ^ (row&7))<<3)];
            }
            #pragma unroll
            for (int j=0;j<4;j++){
                int row = j*16+l15;
                bK[j] = *(const short8*)&lK[cur][row*64 + (((kc*4+quad) ^ (row&7))<<3)];
            }
            #pragma unroll
            for (int i=0;i<2;i++)
                #pragma unroll
                for (int j=0;j<4;j++)
                    S[i][j] = __builtin_amdgcn_mfma_f32_16x16x32_bf16(aQ[i], bK[j], S[i][j], 0,0,0);
        }

        #pragma unroll
        for (int i=0;i<2;i++){
            #pragma unroll
            for (int r=0;r<4;r++){
                float mx = -1e30f;
                #pragma unroll
                for (int j=0;j<4;j++){
                    int col = kt*64 + j*16 + l15;
                    float s = S[i][j][r]*0.125f + (col < lenT ? 0.f : -10000.f);
                    S[i][j][r] = s;
                    mx = fmaxf(mx, s);
                }
                #pragma unroll
                for (int o=1;o<16;o<<=1) mx = fmaxf(mx, __shfl_xor(mx, o, 64));
                float mn = fmaxf(m_i[i][r], mx);
                float alpha = __expf(m_i[i][r] - mn);
                m_i[i][r] = mn;
                float sm = 0.f;
                #pragma unroll
                for (int j=0;j<4;j++){
                    float pv = __expf(S[i][j][r] - mn);
                    S[i][j][r] = pv;
                    sm += pv;
                }
                #pragma unroll
                for (int o=1;o<16;o<<=1) sm += __shfl_xor(sm, o, 64);
                l_i[i][r] = l_i[i][r]*alpha + sm;
                #pragma unroll
                for (int j=0;j<4;j++) O[i][j][r] *= alpha;
            }
        }

        #pragma unroll
        for (int i=0;i<2;i++)
            #pragma unroll
            for (int j=0;j<4;j++)
                #pragma unroll
                for (int r=0;r<4;r++){
                    int row = w*32 + i*16 + quad*4 + r;
                    int col = j*16 + l15;
                    lP[row*64 + (((col>>3) ^ (row&7))<<3) + (col&7)] = f2b(S[i][j][r]);
                }
        __syncthreads();                         // lP visible
        if (kt+1 < nkt) stage_V(cur^1, kt+1);    // overlaps PV

        #pragma unroll
        for (int kc=0;kc<2;kc++){
            short8 aP[2], bV[4];
            #pragma unroll
            for (int i=0;i<2;i++){
                int row = w*32+i*16+l15;
                aP[i] = *(const short8*)&lP[row*64 + (((kc*4+quad) ^ (row&7))<<3)];
            }
            #pragma unroll
            for (int j=0;j<4;j++){
                int row = j*16+l15;
                bV[j] = *(const short8*)&lV[cur][row*64 + (((kc*4+quad) ^ (row&7))<<3)];
            }
            #pragma unroll
            for (int i=0;i<2;i++)
                #pragma unroll
                for (int j=0;j<4;j++)
                    O[i][j] = __builtin_amdgcn_mfma_f32_16x16x32_bf16(aP[i], bV[j], O[i][j], 0,0,0);
        }
    }

    #pragma unroll
    for (int i=0;i<2;i++)
        #pragma unroll
        for (int j=0;j<4;j++)
            #pragma unroll
            for (int r=0;r<4;r++){
                int row = qt*128 + w*32 + i*16 + quad*4 + r;
                if (row < ST_N)
                    ctx[((long)(b*ST_N+row))*512 + h*64 + j*16 + l15] = f2b(O[i][j][r] / l_i[i][r]);
            }
}

// ---------------- residual + LN (fp32 state + bf16 shadow), bf16 tmp ----------------
__global__ __launch_bounds__(256) void ln_residual_k(
    const bf16* __restrict__ tmp, float* __restrict__ hf, bf16* __restrict__ hb,
    const void* __restrict__ g, const void* __restrict__ bb, long goff,
    void* __restrict__ outp, int is_final, const int* __restrict__ flagp)
{
    const int isf = *flagp;
    const int of32 = is_final && isf;
    long base = (long)blockIdx.x * 512;
    int t = threadIdx.x;
    float v0 = hf[base+t]     + b2f(tmp[base+t]);
    float v1 = hf[base+t+256] + b2f(tmp[base+t+256]);
    __shared__ float red[4];
    float mean = block_reduce_sum(v0+v1, red, t) * (1.f/512.f);
    float d0=v0-mean, d1=v1-mean;
    __syncthreads();
    float var = block_reduce_sum(d0*d0+d1*d1, red, t) * (1.f/512.f);
    float rstd = rsqrtf(var + 1e-12f);
    float o0 = d0*rstd*ldw(g,goff+t,isf) + ldw(bb,goff+t,isf);
    float o1 = d1*rstd*ldw(g,goff+t+256,isf) + ldw(bb,goff+t+256,isf);
    hf[base+t]=o0; hf[base+t+256]=o1;
    hb[base+t]=f2b(o0); hb[base+t+256]=f2b(o1);
    if (of32) {
        ((float*)outp)[base+t]=o0; ((float*)outp)[base+t+256]=o1;
    } else {
        ((bf16*)outp)[base+t]=f2b(o0); ((bf16*)outp)[base+t+256]=f2b(o1);
    }
}

extern "C" void kernel_launch(void* const* d_in, const int* in_sizes, int n_in,
                              void* d_out, int out_size, void* d_ws, size_t ws_size,
                              hipStream_t stream)
{
    (void)in_sizes; (void)n_in; (void)out_size; (void)ws_size;
    const int*  ids   = (const int*) d_in[0];
    const int*  slens = (const int*) d_in[1];
    const void* embed = d_in[2];
    const void* Wdec  = d_in[3];
    const void* bdec  = d_in[4];
    const void* mW1   = d_in[5];
    const void* mb1   = d_in[6];
    const void* mW2   = d_in[7];
    const void* mb2   = d_in[8];
    const void* mlg   = d_in[9];
    const void* mlb   = d_in[10];
    const void* Wq    = d_in[11];
    const void* bq    = d_in[12];
    const void* Wk    = d_in[13];
    const void* bk    = d_in[14];
    const void* Wv    = d_in[15];
    const void* bv    = d_in[16];
    const void* Wo    = d_in[17];
    const void* bo    = d_in[18];
    const void* l1g   = d_in[19];
    const void* l1b   = d_in[20];
    const void* Wi    = d_in[21];
    const void* bi    = d_in[22];
    const void* Wf    = d_in[23];
    const void* bfv   = d_in[24];
    const void* l2g   = d_in[25];
    const void* l2b   = d_in[26];

    char* p = (char*)d_ws;
    auto alloc = [&](size_t bytes)->void* {
        void* r = (void*)p; p += (bytes + 255) & ~(size_t)255; return r; };
    int*   flag  = (int*)  alloc(256);
    float* pmax  = (float*)alloc((size_t)T_N*WCH_N*4);
    float* psum  = (float*)alloc((size_t)T_N*WCH_N*4);
    float* tmf   = (float*)alloc((size_t)T_N*512*4);
    bf16*  tmb   = (bf16*) alloc((size_t)T_N*512*2);
    float* hmem  = (float*)alloc((size_t)64*1024*4);
    bf16*  hrel  = (bf16*) alloc((size_t)64*1024*2);
    float* fcout = (float*)alloc((size_t)64*512*4);
    float* hidf  = (float*)alloc((size_t)NTOK_N*512*4);
    bf16*  hidb  = (bf16*) alloc((size_t)NTOK_N*512*2);
    bf16*  qkvt  = (bf16*) alloc((size_t)NL_N*1536*512*2);
    bf16*  wot   = (bf16*) alloc((size_t)NL_N*512*512*2);
    bf16*  wit   = (bf16*) alloc((size_t)NL_N*2048*512*2);
    bf16*  wft   = (bf16*) alloc((size_t)NL_N*512*2048*2);
    bf16*  bqkv  = (bf16*) alloc((size_t)NL_N*1536*2);
    // R1 union (time-disjoint): prelude [wdb 3.84M | W1t 61.5M | W2t 1M] <-> [qkv 55.25M] <-> [ffb 73.66M]
    char*  R1    = (char*) alloc((size_t)NTOK_N*2048*2);
    bf16*  wdb   = (bf16*)R1;
    bf16*  W1t   = (bf16*)(R1 + (size_t)64*VBP_N*2);
    bf16*  W2t   = (bf16*)(R1 + (size_t)64*VBP_N*2 + (size_t)1024*VBP_N*2);
    bf16*  qkv   = (bf16*)R1;
    bf16*  ffb   = (bf16*)R1;
    // RU2: ctx (18.42M) + [Vt 18.87M <-> tmp16 18.42M]
    bf16*  ctx   = (bf16*) alloc((size_t)NTOK_N*512*2);
    char*  RU2   = (char*) alloc((size_t)NTOK_N*512*4);
    bf16*  Vt    = (bf16*)RU2;
    bf16*  tmp16 = (bf16*)RU2;
    // total ~= 210 MB

    detect_k<<<1,256,0,stream>>>((const unsigned int*)embed, flag);

    // topic memory: parallel softmax -> FC1 (MFMA, K-split atomic) -> relu -> FC2 (MFMA) -> LN
    zero_u32_k<<<((64L*VBP_N/2)+255)/256,256,0,stream>>>((unsigned int*)wdb, 64L*VBP_N/2);
    zero_u32_k<<<((64L*1024)+255)/256,256,0,stream>>>((unsigned int*)hmem, 64L*1024);
    wd_partmax_k<<<dim3(WCH_N,T_N),256,0,stream>>>(Wdec,bdec,pmax,flag);
    wd_partsum_k<<<dim3(WCH_N,T_N),256,0,stream>>>(Wdec,bdec,pmax,psum,flag);
    wd_write_k  <<<dim3(WCH_N,T_N),256,0,stream>>>(Wdec,bdec,pmax,psum,wdb,flag);
    transpose_k<<<dim3(32,VBP_N/32,1),256,0,stream>>>(mW1, W1t, VBP_N, 1024, 0L, 0L, VB_N, flag);
    transpose_k<<<dim3(16,32,1),256,0,stream>>>(mW2, W2t, 1024, 512, 0L, 0L, 1024, flag);
    gemm_k<64,128,EPI_ATOMIC><<<dim3(8,1,32),256,0,stream>>>(
        wdb, W1t, hmem, nullptr, 0,
        64, 1024, VBP_N, VBP_N, VBP_N, 1024, 1024, 960, flag);
    relu_bias_k<<<64,256,0,stream>>>(hmem, mb1, hrel, flag);
    gemm_k<64,128,EPI_F32><<<dim3(4,1,1),256,0,stream>>>(
        hrel, W2t, fcout, mb2, 0,
        64, 512, 1024, 1024, 1024, 512, 512, 0, flag);
    ln_topic_k<<<T_N,256,0,stream>>>(fcout, mlg, mlb, tmf, tmb, flag);
    embed_insert_k<<<dim3(ST_N,B_N),256,0,stream>>>(ids, slens, embed, tmf, tmb, hidf, hidb, flag);

    // weight prep (canonical bf16, [N][K] layouts)
    transpose_k<<<dim3(16,16,NL_N),256,0,stream>>>(Wq, qkvt,          512, 512, 262144L, 786432L, 512, flag);
    transpose_k<<<dim3(16,16,NL_N),256,0,stream>>>(Wk, qkvt+262144,   512, 512, 262144L, 786432L, 512, flag);
    transpose_k<<<dim3(16,16,NL_N),256,0,stream>>>(Wv, qkvt+524288,   512, 512, 262144L, 786432L, 512, flag);
    transpose_k<<<dim3(16,16,NL_N),256,0,stream>>>(Wo, wot,           512, 512, 262144L, 262144L, 512, flag);
    transpose_k<<<dim3(64,16,NL_N),256,0,stream>>>(Wi, wit,           512, 2048, 1048576L, 1048576L, 512, flag);
    transpose_k<<<dim3(16,64,NL_N),256,0,stream>>>(Wf, wft,           2048, 512, 1048576L, 1048576L, 2048, flag);
    concat_bias_k<<<(NL_N*1536+255)/256,256,0,stream>>>(bq,bk,bv,bqkv,flag);

    for (int l=0;l<NL_N;l++) {
        gemm_k<128,128,EPI_BF16><<<dim3(12,141,1),256,0,stream>>>(
            hidb, qkvt + (size_t)l*786432, qkv, bqkv, (long)l*1536,
            NTOK_N, 1536, 512, 512, 512, 1536, 1536, 0, flag);
        transpose_v_k<<<dim3(18,1,256),256,0,stream>>>(qkv, Vt, slens);
        flash_k<<<dim3(5,1,256),256,0,stream>>>(qkv, Vt, ctx, slens);
        gemm_k<128,128,EPI_BF16R><<<dim3(4,141,1),256,0,stream>>>(
            ctx, wot + (size_t)l*262144, tmp16, bo, (long)l*512,
            NTOK_N, 512, 512, 512, 512, 512, 512, 0, flag);
        ln_residual_k<<<NTOK_N,256,0,stream>>>(tmp16, hidf, hidb, l1g, l1b, (long)l*512,
                                               hidb, 0, flag);
        gemm_k<128,128,EPI_GELU><<<dim3(16,141,1),256,0,stream>>>(
            hidb, wit + (size_t)l*1048576, ffb, bi, (long)l*2048,
            NTOK_N, 2048, 512, 512, 512, 2048, 2048, 0, flag);
        gemm_k<128,128,EPI_BF16R><<<dim3(4,141,1),256,0,stream>>>(
            ffb, wft + (size_t)l*1048576, tmp16, bfv, (long)l*512,
            NTOK_N, 512, 2048, 2048, 2048, 512, 512, 0, flag);
        ln_residual_k<<<NTOK_N,256,0,stream>>>(tmp16, hidf, hidb, l2g, l2b, (long)l*512,
                                               (l == NL_N-1) ? d_out : (void*)hidb,
                                               (l == NL_N-1) ? 1 : 0, flag);
    }
}

// Round 3
// 1702.335 us; speedup vs baseline: 1.1218x; 1.1218x over previous
//
#include <hip/hip_runtime.h>
#include <hip/hip_bf16.h>
#include <math.h>

using bf16 = __hip_bfloat16;
typedef __attribute__((ext_vector_type(4))) float f32x4;
typedef __attribute__((ext_vector_type(8))) short short8;

#define B_N 32
#define S_N 512
#define T_N 50
#define H_N 8
#define NL_N 4
#define VB_N 30000
#define VBP_N 30016          // VB padded to mult of 64
#define ST_N 562
#define STP_N 576
#define NTOK_N (B_N*ST_N)   // 17984
#define WCH_N 16             // softmax_wdec column chunks
#define WCW_N 1875           // 30000/16

__device__ __forceinline__ float b2f(bf16 x){ return __bfloat162float(x); }
__device__ __forceinline__ bf16  f2b(float x){ return __float2bfloat16(x); }
// flag-aware raw-input load: f==1 -> buffer is float32, else bf16
__device__ __forceinline__ float ldw(const void* p, long i, int f){
    return f ? ((const float*)p)[i] : __bfloat162float(((const bf16*)p)[i]);
}

__device__ __forceinline__ void load_lds16(const void* g, void* l){
    __builtin_amdgcn_global_load_lds((const __attribute__((address_space(1))) void*)g,
                                     (__attribute__((address_space(3))) void*)l, 16, 0, 0);
}

// XCD-aware bijective block swizzle (m204): consecutive flat ids round-robin
// over 8 XCDs in hardware; this remap hands each XCD a CONTIGUOUS chunk of
// the flat id space so blocks sharing operand panels land in the same L2.
__device__ __forceinline__ int xcd_swizzle(int flat, int nwg){
    int xcd = flat & 7, rest = flat >> 3;
    int q = nwg >> 3, r = nwg & 7;
    return (xcd < r ? xcd*(q+1) : r*(q+1) + (xcd-r)*q) + rest;
}

__device__ __forceinline__ float block_reduce_max(float v, float* red, int t){
    for (int o=32;o>0;o>>=1) v = fmaxf(v, __shfl_down(v,o,64));
    int w=t>>6, lane=t&63;
    if (lane==0) red[w]=v;
    __syncthreads();
    return fmaxf(fmaxf(red[0],red[1]),fmaxf(red[2],red[3]));
}
__device__ __forceinline__ float block_reduce_sum(float v, float* red, int t){
    for (int o=32;o>0;o>>=1) v += __shfl_down(v,o,64);
    int w=t>>6, lane=t&63;
    if (lane==0) red[w]=v;
    __syncthreads();
    return red[0]+red[1]+red[2]+red[3];
}

// ---------------- dtype detector ----------------
__global__ __launch_bounds__(256) void detect_k(const unsigned int* __restrict__ w, int* flag)
{
    int t = threadIdx.x;
    float s = 0.f;
    for (int i=t;i<4096;i+=256){ int e = (w[i]>>7)&0xFF; s += fabsf((float)e - 120.f); }
    __shared__ float red[4];
    for (int o=32;o>0;o>>=1) s += __shfl_down(s,o,64);
    int wv=t>>6, lane=t&63;
    if (lane==0) red[wv]=s;
    __syncthreads();
    if (t==0) flag[0] = ((red[0]+red[1]+red[2]+red[3]) * (1.f/4096.f) > 20.f) ? 1 : 0;
}

__global__ void zero_u32_k(unsigned int* p, long n){
    long i = (long)blockIdx.x*256 + threadIdx.x;
    if (i < n) p[i] = 0u;
}

// ---------------- topic memory: parallel W_dec softmax ----------------
__global__ __launch_bounds__(256) void wd_partmax_k(
    const void* __restrict__ Wd, const void* __restrict__ bd,
    float* __restrict__ pmax, const int* __restrict__ flagp)
{
    const int isf = *flagp;
    int ch = blockIdx.x, r = blockIdx.y, t = threadIdx.x;
    int c0 = ch*WCW_N, c1 = c0 + WCW_N;
    __shared__ float red[4];
    float mx = -1e30f;
    for (int c=c0+t;c<c1;c+=256) mx = fmaxf(mx, ldw(Wd,(long)r*VB_N+c,isf) + ldw(bd,c,isf));
    mx = block_reduce_max(mx, red, t);
    if (t==0) pmax[r*WCH_N + ch] = mx;
}

__global__ __launch_bounds__(256) void wd_partsum_k(
    const void* __restrict__ Wd, const void* __restrict__ bd,
    const float* __restrict__ pmax, float* __restrict__ psum, const int* __restrict__ flagp)
{
    const int isf = *flagp;
    int ch = blockIdx.x, r = blockIdx.y, t = threadIdx.x;
    float mx = -1e30f;
    #pragma unroll
    for (int i=0;i<WCH_N;i++) mx = fmaxf(mx, pmax[r*WCH_N+i]);
    int c0 = ch*WCW_N, c1 = c0 + WCW_N;
    __shared__ float red[4];
    float sm = 0.f;
    for (int c=c0+t;c<c1;c+=256) sm += __expf(ldw(Wd,(long)r*VB_N+c,isf) + ldw(bd,c,isf) - mx);
    sm = block_reduce_sum(sm, red, t);
    if (t==0) psum[r*WCH_N + ch] = sm;
}

__global__ __launch_bounds__(256) void wd_write_k(
    const void* __restrict__ Wd, const void* __restrict__ bd,
    const float* __restrict__ pmax, const float* __restrict__ psum,
    bf16* __restrict__ wdb, const int* __restrict__ flagp)
{
    const int isf = *flagp;
    int ch = blockIdx.x, r = blockIdx.y, t = threadIdx.x;
    float mx = -1e30f, sm = 0.f;
    #pragma unroll
    for (int i=0;i<WCH_N;i++){ mx = fmaxf(mx, pmax[r*WCH_N+i]); sm += psum[r*WCH_N+i]; }
    float inv = 1.f/sm;
    int c0 = ch*WCW_N, c1 = c0 + WCW_N;
    for (int c=c0+t;c<c1;c+=256)
        wdb[(long)r*VBP_N + c] = f2b(__expf(ldw(Wd,(long)r*VB_N+c,isf) + ldw(bd,c,isf) - mx)*inv);
}

// hrel[64][1024] bf16 = relu(hmem + b1), rows >= T_N zeroed
__global__ __launch_bounds__(256) void relu_bias_k(
    const float* __restrict__ hmem, const void* __restrict__ b1,
    bf16* __restrict__ hrel, const int* __restrict__ flagp)
{
    const int isf = *flagp;
    int r = blockIdx.x, t = threadIdx.x;
    for (int c=t;c<1024;c+=256){
        float v = (r < T_N) ? fmaxf(hmem[r*1024+c] + ldw(b1,c,isf), 0.f) : 0.f;
        hrel[r*1024+c] = f2b(v);
    }
}

// plain LN over 50 rows of fcout[64][512] (bias b2 already added in GEMM epilogue)
__global__ __launch_bounds__(256) void ln_topic_k(
    const float* __restrict__ fcout,
    const void* __restrict__ lg, const void* __restrict__ lb,
    float* __restrict__ tmf, bf16* __restrict__ tmb, const int* __restrict__ flagp)
{
    const int isf = *flagp;
    int r = blockIdx.x, t = threadIdx.x;
    float a0 = fcout[r*512+t], a1 = fcout[r*512+t+256];
    __shared__ float red[4];
    float mean = block_reduce_sum(a0+a1, red, t) * (1.f/512.f);
    float d0=a0-mean, d1=a1-mean;
    __syncthreads();
    float var = block_reduce_sum(d0*d0+d1*d1, red, t) * (1.f/512.f);
    float rstd = rsqrtf(var + 1e-12f);
    float o0 = d0*rstd*ldw(lg,t,isf) + ldw(lb,t,isf);
    float o1 = d1*rstd*ldw(lg,t+256,isf) + ldw(lb,t+256,isf);
    tmf[r*512+t]=o0; tmf[r*512+t+256]=o1;
    tmb[r*512+t]=f2b(o0); tmb[r*512+t+256]=f2b(o1);
}

// ---------------- embedding + ragged insert ----------------
__global__ __launch_bounds__(256) void embed_insert_k(
    const int* __restrict__ ids, const int* __restrict__ lens,
    const void* __restrict__ embed, const float* __restrict__ tmf,
    const bf16* __restrict__ tmb, float* __restrict__ hf, bf16* __restrict__ hb,
    const int* __restrict__ flagp)
{
    const int isf = *flagp;
    int j = blockIdx.x, b = blockIdx.y, t = threadIdx.x;
    int L = lens[b]; L = L<1?1:(L>S_N?S_N:L);
    long orow = ((long)b*ST_N + j)*512;
    if (j >= L && j < L + T_N) {
        int m = j - L;
        for (int c=t;c<512;c+=256){ float v = tmf[m*512+c]; hf[orow+c]=v; hb[orow+c]=tmb[m*512+c]; }
    } else {
        int sj = (j < L) ? j : j - T_N;   // in [0, 511]
        int id = ids[b*S_N + sj];
        for (int c=t;c<512;c+=256){ float e = ldw(embed,(long)id*512+c,isf); hf[orow+c]=e; hb[orow+c]=f2b(e); }
    }
}

// ---------------- weight prep ----------------
// dst[z*dstride + (n0+n)*R + (k0+k)] = src[z*sstride + min(k0+k,Ksrc-1)*C + (n0+n)]
__global__ __launch_bounds__(256) void transpose_k(
    const void* __restrict__ src, bf16* __restrict__ dst,
    int R, int C, long sstride, long dstride, int Ksrc, const int* __restrict__ flagp)
{
    const int isf = *flagp;
    __shared__ bf16 tile[32][33];
    int n0 = blockIdx.x * 32, k0 = blockIdx.y * 32, z = blockIdx.z;
    int t = threadIdx.x;
    int nl = t & 31, kb = t >> 5;
    #pragma unroll
    for (int i=0;i<4;i++) {
        int k = k0 + kb + i*8; k = k < Ksrc ? k : Ksrc-1;
        tile[kb+i*8][nl] = f2b(ldw(src, z*sstride + (long)k*C + n0+nl, isf));
    }
    __syncthreads();
    int kl = t & 31, nb = t >> 5;
    #pragma unroll
    for (int i=0;i<4;i++) {
        int n = nb + i*8;
        dst[z*dstride + (long)(n0+n)*R + k0+kl] = tile[kl][n];
    }
}

__global__ void concat_bias_k(const void* bq, const void* bk, const void* bv, bf16* out,
                              const int* __restrict__ flagp){
    const int isf = *flagp;
    int i = blockIdx.x*256 + threadIdx.x;
    if (i >= NL_N*1536) return;
    int l = i/1536, n = i%1536;
    float v = (n<512) ? ldw(bq,l*512+n,isf) : (n<1024 ? ldw(bk,l*512+n-512,isf) : ldw(bv,l*512+n-1024,isf));
    out[i] = f2b(v);
}

// Vt[z][n][k]: n = head dim (64), k = key (576, zero pad k>=562); z = b*8+h over all 256
// Early-exit: flash only reads k-tiles < ceil((L+T)/64), skip blocks beyond that.
__global__ __launch_bounds__(256) void transpose_v_k(
    const bf16* __restrict__ qkv, bf16* __restrict__ Vt, const int* __restrict__ slens)
{
    __shared__ bf16 tl[64*33];
    int k0 = blockIdx.x * 32, z = blockIdx.z;
    int b = z >> 3, h = z & 7;
    int L = slens[b]; L = L<1?1:(L>S_N?S_N:L);
    int kmax = ((L + T_N + 63) >> 6) << 6;   // active k region rounded to 64
    if (k0 >= kmax) return;
    int t = threadIdx.x;
    int n = t & 63, kb = t >> 6;
    #pragma unroll
    for (int i=0;i<8;i++) {
        int kl = kb + 4*i;
        int kg = k0 + kl;
        bf16 v = (kg < ST_N) ? qkv[((long)(b*ST_N + kg))*1536 + 1024 + h*64 + n] : f2b(0.f);
        tl[n*33 + kl] = v;
    }
    __syncthreads();
    int kk = t & 31, nb = t >> 5;
    #pragma unroll
    for (int i=0;i<8;i++) {
        int nn = nb + 8*i;
        Vt[((long)z*64 + nn)*STP_N + k0 + kk] = tl[nn*33 + kk];
    }
}

// ---------------- MFMA GEMM: C = A[M,K] @ Bt[N,K]^T ----------------
// BK=64 (128 B rows, full 32-bank span) with XOR-8 chunk swizzle:
// LDS chunk p of row r holds global chunk p^(r&7); per 16-lane phase the 8
// chunk positions are hit exactly 2x -> 2-way (free, m136). K must be mult of 64.
// XCD chunk swizzle on the block grid: x-fast flat ids -> contiguous per-XCD
// ranges, so the 16ish column-tile blocks sharing an A row-panel hit one L2.
constexpr int EPI_BF16=0, EPI_F32=1, EPI_GELU=2, EPI_ATOMIC=3, EPI_BF16R=4;

template<int BM, int BN, int MODE>
__global__ __launch_bounds__(256,4) void gemm_k(
    const bf16* __restrict__ Ag, const bf16* __restrict__ Bg, void* __restrict__ Cg,
    const void* __restrict__ bias, long bias_off,
    int M, int N, int K, int lda, int ldb, int ldc, int Nst, int kch,
    const int* __restrict__ flagp)
{
    const int isf = *flagp;
    __shared__ __align__(16) bf16 lA[BM*64];
    __shared__ __align__(16) bf16 lB[BN*64];
    const int tid = threadIdx.x;
    const int nwg = gridDim.x * gridDim.y;
    const int flat = blockIdx.y * gridDim.x + blockIdx.x;
    const int swz = xcd_swizzle(flat, nwg);
    const int tile_m = (swz / gridDim.x) * BM;
    const int tile_n = (swz % gridDim.x) * BN;

    bf16*  C16 = (bf16*)Cg;
    float* C32 = (float*)Cg;

    constexpr int WM = BM/2, WN = BN/2, MI = WM/16, NI = WN/16;
    const int w = tid>>6, lane = tid&63;
    const int wm = w>>1, wn = w&1;
    const int quad = lane>>4, lrow = lane&15;

    f32x4 zero = {0.f,0.f,0.f,0.f};
    f32x4 acc[MI][NI];
    #pragma unroll
    for (int i=0;i<MI;i++)
        #pragma unroll
        for (int j=0;j<NI;j++) acc[i][j] = zero;

    int ks = 0, ke = K;
    if (kch > 0) { ks = blockIdx.z * kch; ke = ks + kch; if (ke > K) ke = K; }

    for (int k0=ks;k0<ke;k0+=64) {
        __syncthreads();
        #pragma unroll
        for (int r=0;r<BM/32;r++) {
            int e = r*256 + tid;             // [0, BM*8)
            int row = e>>3, c8 = (e&7) ^ (row&7);
            int gr = tile_m + row; gr = gr < M ? gr : M-1;
            load_lds16(Ag + (long)gr*lda + k0 + c8*8, &lA[e*8]);
        }
        #pragma unroll
        for (int r=0;r<BN/32;r++) {
            int e = r*256 + tid;
            int row = e>>3, c8 = (e&7) ^ (row&7);
            int gr = tile_n + row; gr = gr < N ? gr : N-1;
            load_lds16(Bg + (long)gr*ldb + k0 + c8*8, &lB[e*8]);
        }
        __syncthreads();
        #pragma unroll
        for (int kc=0;kc<2;kc++){
            short8 afr[MI], bfr[NI];
            #pragma unroll
            for (int i=0;i<MI;i++){
                int row = wm*WM + i*16 + lrow;
                afr[i] = *(const short8*)&lA[row*64 + (((kc*4+quad) ^ (row&7))<<3)];
            }
            #pragma unroll
            for (int j=0;j<NI;j++){
                int row = wn*WN + j*16 + lrow;
                bfr[j] = *(const short8*)&lB[row*64 + (((kc*4+quad) ^ (row&7))<<3)];
            }
            #pragma unroll
            for (int i=0;i<MI;i++)
                #pragma unroll
                for (int j=0;j<NI;j++)
                    acc[i][j] = __builtin_amdgcn_mfma_f32_16x16x32_bf16(afr[i], bfr[j], acc[i][j], 0, 0, 0);
        }
    }

    #pragma unroll
    for (int i=0;i<MI;i++) {
        #pragma unroll
        for (int j=0;j<NI;j++) {
            int col = tile_n + wn*WN + j*16 + lrow;
            int rb  = tile_m + wm*WM + i*16 + quad*4;
            #pragma unroll
            for (int r=0;r<4;r++) {
                int row = rb + r;
                if (row >= M || col >= Nst) continue;
                float v = acc[i][j][r];
                if constexpr (MODE == EPI_BF16) {
                    C16[(long)row*ldc + col] = f2b(v + b2f(((const bf16*)bias)[bias_off + col]));
                } else if constexpr (MODE == EPI_F32) {
                    C32[(long)row*ldc + col] = v + ldw(bias, bias_off + col, isf);
                } else if constexpr (MODE == EPI_GELU) {
                    float x = v + ldw(bias, bias_off + col, isf);
                    C16[(long)row*ldc + col] = f2b(0.5f*x*(1.f + erff(x*0.70710678118654752f)));
                } else if constexpr (MODE == EPI_BF16R) {
                    C16[(long)row*ldc + col] = f2b(v + ldw(bias, bias_off + col, isf));
                } else { // EPI_ATOMIC
                    atomicAdd(&C32[(long)row*ldc + col], v);
                }
            }
        }
    }
}

// ---------------- flash attention ----------------
// Early-exit over KV tiles (bit-identical: masked tiles give exp()==0.0f).
// K/V double-buffered: next-K staged after barrier-1 (hides under QK+softmax),
// next-V staged after barrier-2 (hides under PV). LDS 64KB = 2 blocks/CU,
// matching the launch_bounds cap, so occupancy is unchanged.
// XCD swizzle: the 5 q-tiles of one (b,h) share its K/V panels -> one L2.
__global__ __launch_bounds__(256,2) void flash_k(
    const bf16* __restrict__ qkv, const bf16* __restrict__ Vt,
    bf16* __restrict__ ctx, const int* __restrict__ slens)
{
    __shared__ __align__(16) bf16 lQ[128*64];
    __shared__ __align__(16) bf16 lK[2][64*64];
    __shared__ __align__(16) bf16 lV[2][64*64];
    __shared__ __align__(16) bf16 lP[128*64];
    const int nwg = gridDim.x * gridDim.z;
    const int flat = blockIdx.z * gridDim.x + blockIdx.x;
    const int swz = xcd_swizzle(flat, nwg);
    const int z = swz / gridDim.x, b = z>>3, h = z&7;
    const int qt = swz % gridDim.x;
    const int tid = threadIdx.x;
    const int w = tid>>6, lane = tid&63;
    const int quad = lane>>4, l15 = lane&15;
    int L = slens[b]; L = L<1?1:(L>S_N?S_N:L);
    const int lenT = L + T_N;
    const int nkt = (lenT + 63) >> 6;   // active KV tiles (wave-uniform)

    #pragma unroll
    for (int rr=0;rr<4;rr++){
        int ci = rr*256 + tid;
        int row = ci>>3, c8 = (ci&7) ^ (row&7);
        int gr = qt*128 + row; gr = gr < ST_N ? gr : ST_N-1;
        load_lds16(qkv + ((long)(b*ST_N+gr))*1536 + h*64 + c8*8, &lQ[ci*8]);
    }

    auto stage_K = [&](int buf, int kt){
        #pragma unroll
        for (int rr=0;rr<2;rr++){
            int ci = rr*256+tid;
            int row = ci>>3, c8 = (ci&7) ^ (row&7);
            int kr = kt*64+row; kr = kr < ST_N ? kr : ST_N-1;
            load_lds16(qkv + ((long)(b*ST_N+kr))*1536 + 512 + h*64 + c8*8, &lK[buf][ci*8]);
        }
    };
    auto stage_V = [&](int buf, int kt){
        #pragma unroll
        for (int rr=0;rr<2;rr++){
            int ci = rr*256+tid;
            int n = ci>>3, c8 = (ci&7) ^ (n&7);
            load_lds16(Vt + ((long)z*64+n)*STP_N + kt*64 + c8*8, &lV[buf][ci*8]);
        }
    };

    stage_K(0, 0);
    stage_V(0, 0);

    f32x4 zerov = {0.f,0.f,0.f,0.f};
    f32x4 O[2][4];
    float m_i[2][4], l_i[2][4];
    #pragma unroll
    for (int i=0;i<2;i++){
        #pragma unroll
        for (int j=0;j<4;j++) O[i][j] = zerov;
        #pragma unroll
        for (int r=0;r<4;r++){ m_i[i][r]=-1e30f; l_i[i][r]=0.f; }
    }

    for (int kt=0; kt<nkt; kt++){
        const int cur = kt & 1;
        __syncthreads();                         // K[cur],V[cur] ready; lP reads done
        if (kt+1 < nkt) stage_K(cur^1, kt+1);    // overlaps QK + softmax

        f32x4 S[2][4];
        #pragma unroll
        for (int i=0;i<2;i++)
            #pragma unroll
            for (int j=0;j<4;j++) S[i][j] = zerov;
        #pragma unroll
        for (int kc=0;kc<2;kc++){
            short8 aQ[2], bK[4];
            #pragma unroll
            for (int i=0;i<2;i++){
                int row = w*32+i*16+l15;
                aQ[i] = *(const short8*)&lQ[row*64 + (((kc*4+quad) ^ (row&7))<<3)];
            }
            #pragma unroll
            for (int j=0;j<4;j++){
                int row = j*16+l15;
                bK[j] = *(const short8*)&lK[cur][row*64 + (((kc*4+quad) ^ (row&7))<<3)];
            }
            #pragma unroll
            for (int i=0;i<2;i++)
                #pragma unroll
                for (int j=0;j<4;j++)
                    S[i][j] = __builtin_amdgcn_mfma_f32_16x16x32_bf16(aQ[i], bK[j], S[i][j], 0,0,0);
        }

        #pragma unroll
        for (int i=0;i<2;i++){
            #pragma unroll
            for (int r=0;r<4;r++){
                float mx = -1e30f;
                #pragma unroll
                for (int j=0;j<4;j++){
                    int col = kt*64 + j*16 + l15;
                    float s = S[i][j][r]*0.125f + (col < lenT ? 0.f : -10000.f);
                    S[i][j][r] = s;
                    mx = fmaxf(mx, s);
                }
                #pragma unroll
                for (int o=1;o<16;o<<=1) mx = fmaxf(mx, __shfl_xor(mx, o, 64));
                float mn = fmaxf(m_i[i][r], mx);
                float alpha = __expf(m_i[i][r] - mn);
                m_i[i][r] = mn;
                float sm = 0.f;
                #pragma unroll
                for (int j=0;j<4;j++){
                    float pv = __expf(S[i][j][r] - mn);
                    S[i][j][r] = pv;
                    sm += pv;
                }
                #pragma unroll
                for (int o=1;o<16;o<<=1) sm += __shfl_xor(sm, o, 64);
                l_i[i][r] = l_i[i][r]*alpha + sm;
                #pragma unroll
                for (int j=0;j<4;j++) O[i][j][r] *= alpha;
            }
        }

        #pragma unroll
        for (int i=0;i<2;i++)
            #pragma unroll
            for (int j=0;j<4;j++)
                #pragma unroll
                for (int r=0;r<4;r++){
                    int row = w*32 + i*16 + quad*4 + r;
                    int col = j*16 + l15;
                    lP[row*64 + (((col>>3) ^ (row&7))<<3) + (col&7)] = f2b(S[i][j][r]);
                }
        __syncthreads();                         // lP visible
        if (kt+1 < nkt) stage_V(cur^1, kt+1);    // overlaps PV

        #pragma unroll
        for (int kc=0;kc<2;kc++){
            short8 aP[2], bV[4];
            #pragma unroll
            for (int i=0;i<2;i++){
                int row = w*32+i*16+l15;
                aP[i] = *(const short8*)&lP[row*64 + (((kc*4+quad) ^ (row&7))<<3)];
            }
            #pragma unroll
            for (int j=0;j<4;j++){
                int row = j*16+l15;
                bV[j] = *(const short8*)&lV[cur][row*64 + (((kc*4+quad) ^ (row&7))<<3)];
            }
            #pragma unroll
            for (int i=0;i<2;i++)
                #pragma unroll
                for (int j=0;j<4;j++)
                    O[i][j] = __builtin_amdgcn_mfma_f32_16x16x32_bf16(aP[i], bV[j], O[i][j], 0,0,0);
        }
    }

    #pragma unroll
    for (int i=0;i<2;i++)
        #pragma unroll
        for (int j=0;j<4;j++)
            #pragma unroll
            for (int r=0;r<4;r++){
                int row = qt*128 + w*32 + i*16 + quad*4 + r;
                if (row < ST_N)
                    ctx[((long)(b*ST_N+row))*512 + h*64 + j*16 + l15] = f2b(O[i][j][r] / l_i[i][r]);
            }
}

// ---------------- residual + LN (fp32 state + bf16 shadow), bf16 tmp ----------------
__global__ __launch_bounds__(256) void ln_residual_k(
    const bf16* __restrict__ tmp, float* __restrict__ hf, bf16* __restrict__ hb,
    const void* __restrict__ g, const void* __restrict__ bb, long goff,
    void* __restrict__ outp, int is_final, const int* __restrict__ flagp)
{
    const int isf = *flagp;
    const int of32 = is_final && isf;
    long base = (long)blockIdx.x * 512;
    int t = threadIdx.x;
    float v0 = hf[base+t]     + b2f(tmp[base+t]);
    float v1 = hf[base+t+256] + b2f(tmp[base+t+256]);
    __shared__ float red[4];
    float mean = block_reduce_sum(v0+v1, red, t) * (1.f/512.f);
    float d0=v0-mean, d1=v1-mean;
    __syncthreads();
    float var = block_reduce_sum(d0*d0+d1*d1, red, t) * (1.f/512.f);
    float rstd = rsqrtf(var + 1e-12f);
    float o0 = d0*rstd*ldw(g,goff+t,isf) + ldw(bb,goff+t,isf);
    float o1 = d1*rstd*ldw(g,goff+t+256,isf) + ldw(bb,goff+t+256,isf);
    hf[base+t]=o0; hf[base+t+256]=o1;
    hb[base+t]=f2b(o0); hb[base+t+256]=f2b(o1);
    if (of32) {
        ((float*)outp)[base+t]=o0; ((float*)outp)[base+t+256]=o1;
    } else {
        ((bf16*)outp)[base+t]=f2b(o0); ((bf16*)outp)[base+t+256]=f2b(o1);
    }
}

extern "C" void kernel_launch(void* const* d_in, const int* in_sizes, int n_in,
                              void* d_out, int out_size, void* d_ws, size_t ws_size,
                              hipStream_t stream)
{
    (void)in_sizes; (void)n_in; (void)out_size; (void)ws_size;
    const int*  ids   = (const int*) d_in[0];
    const int*  slens = (const int*) d_in[1];
    const void* embed = d_in[2];
    const void* Wdec  = d_in[3];
    const void* bdec  = d_in[4];
    const void* mW1   = d_in[5];
    const void* mb1   = d_in[6];
    const void* mW2   = d_in[7];
    const void* mb2   = d_in[8];
    const void* mlg   = d_in[9];
    const void* mlb   = d_in[10];
    const void* Wq    = d_in[11];
    const void* bq    = d_in[12];
    const void* Wk    = d_in[13];
    const void* bk    = d_in[14];
    const void* Wv    = d_in[15];
    const void* bv    = d_in[16];
    const void* Wo    = d_in[17];
    const void* bo    = d_in[18];
    const void* l1g   = d_in[19];
    const void* l1b   = d_in[20];
    const void* Wi    = d_in[21];
    const void* bi    = d_in[22];
    const void* Wf    = d_in[23];
    const void* bfv   = d_in[24];
    const void* l2g   = d_in[25];
    const void* l2b   = d_in[26];

    char* p = (char*)d_ws;
    auto alloc = [&](size_t bytes)->void* {
        void* r = (void*)p; p += (bytes + 255) & ~(size_t)255; return r; };
    int*   flag  = (int*)  alloc(256);
    float* pmax  = (float*)alloc((size_t)T_N*WCH_N*4);
    float* psum  = (float*)alloc((size_t)T_N*WCH_N*4);
    float* tmf   = (float*)alloc((size_t)T_N*512*4);
    bf16*  tmb   = (bf16*) alloc((size_t)T_N*512*2);
    float* hmem  = (float*)alloc((size_t)64*1024*4);
    bf16*  hrel  = (bf16*) alloc((size_t)64*1024*2);
    float* fcout = (float*)alloc((size_t)64*512*4);
    float* hidf  = (float*)alloc((size_t)NTOK_N*512*4);
    bf16*  hidb  = (bf16*) alloc((size_t)NTOK_N*512*2);
    bf16*  qkvt  = (bf16*) alloc((size_t)NL_N*1536*512*2);
    bf16*  wot   = (bf16*) alloc((size_t)NL_N*512*512*2);
    bf16*  wit   = (bf16*) alloc((size_t)NL_N*2048*512*2);
    bf16*  wft   = (bf16*) alloc((size_t)NL_N*512*2048*2);
    bf16*  bqkv  = (bf16*) alloc((size_t)NL_N*1536*2);
    // R1 union (time-disjoint): prelude [wdb 3.84M | W1t 61.5M | W2t 1M] <-> [qkv 55.25M] <-> [ffb 73.66M]
    char*  R1    = (char*) alloc((size_t)NTOK_N*2048*2);
    bf16*  wdb   = (bf16*)R1;
    bf16*  W1t   = (bf16*)(R1 + (size_t)64*VBP_N*2);
    bf16*  W2t   = (bf16*)(R1 + (size_t)64*VBP_N*2 + (size_t)1024*VBP_N*2);
    bf16*  qkv   = (bf16*)R1;
    bf16*  ffb   = (bf16*)R1;
    // RU2: ctx (18.42M) + [Vt 18.87M <-> tmp16 18.42M]
    bf16*  ctx   = (bf16*) alloc((size_t)NTOK_N*512*2);
    char*  RU2   = (char*) alloc((size_t)NTOK_N*512*4);
    bf16*  Vt    = (bf16*)RU2;
    bf16*  tmp16 = (bf16*)RU2;
    // total ~= 210 MB

    detect_k<<<1,256,0,stream>>>((const unsigned int*)embed, flag);

    // topic memory: parallel softmax -> FC1 (MFMA, K-split atomic) -> relu -> FC2 (MFMA) -> LN
    zero_u32_k<<<((64L*VBP_N/2)+255)/256,256,0,stream>>>((unsigned int*)wdb, 64L*VBP_N/2);
    zero_u32_k<<<((64L*1024)+255)/256,256,0,stream>>>((unsigned int*)hmem, 64L*1024);
    wd_partmax_k<<<dim3(WCH_N,T_N),256,0,stream>>>(Wdec,bdec,pmax,flag);
    wd_partsum_k<<<dim3(WCH_N,T_N),256,0,stream>>>(Wdec,bdec,pmax,psum,flag);
    wd_write_k  <<<dim3(WCH_N,T_N),256,0,stream>>>(Wdec,bdec,pmax,psum,wdb,flag);
    transpose_k<<<dim3(32,VBP_N/32,1),256,0,stream>>>(mW1, W1t, VBP_N, 1024, 0L, 0L, VB_N, flag);
    transpose_k<<<dim3(16,32,1),256,0,stream>>>(mW2, W2t, 1024, 512, 0L, 0L, 1024, flag);
    gemm_k<64,128,EPI_ATOMIC><<<dim3(8,1,32),256,0,stream>>>(
        wdb, W1t, hmem, nullptr, 0,
        64, 1024, VBP_N, VBP_N, VBP_N, 1024, 1024, 960, flag);
    relu_bias_k<<<64,256,0,stream>>>(hmem, mb1, hrel, flag);
    gemm_k<64,128,EPI_F32><<<dim3(4,1,1),256,0,stream>>>(
        hrel, W2t, fcout, mb2, 0,
        64, 512, 1024, 1024, 1024, 512, 512, 0, flag);
    ln_topic_k<<<T_N,256,0,stream>>>(fcout, mlg, mlb, tmf, tmb, flag);
    embed_insert_k<<<dim3(ST_N,B_N),256,0,stream>>>(ids, slens, embed, tmf, tmb, hidf, hidb, flag);

    // weight prep (canonical bf16, [N][K] layouts)
    transpose_k<<<dim3(16,16,NL_N),256,0,stream>>>(Wq, qkvt,          512, 512, 262144L, 786432L, 512, flag);
    transpose_k<<<dim3(16,16,NL_N),256,0,stream>>>(Wk, qkvt+262144,   512, 512, 262144L, 786432L, 512, flag);
    transpose_k<<<dim3(16,16,NL_N),256,0,stream>>>(Wv, qkvt+524288,   512, 512, 262144L, 786432L, 512, flag);
    transpose_k<<<dim3(16,16,NL_N),256,0,stream>>>(Wo, wot,           512, 512, 262144L, 262144L, 512, flag);
    transpose_k<<<dim3(64,16,NL_N),256,0,stream>>>(Wi, wit,           512, 2048, 1048576L, 1048576L, 512, flag);
    transpose_k<<<dim3(16,64,NL_N),256,0,stream>>>(Wf, wft,           2048, 512, 1048576L, 1048576L, 2048, flag);
    concat_bias_k<<<(NL_N*1536+255)/256,256,0,stream>>>(bq,bk,bv,bqkv,flag);

    for (int l=0;l<NL_N;l++) {
        gemm_k<128,128,EPI_BF16><<<dim3(12,141,1),256,0,stream>>>(
            hidb, qkvt + (size_t)l*786432, qkv, bqkv, (long)l*1536,
            NTOK_N, 1536, 512, 512, 512, 1536, 1536, 0, flag);
        transpose_v_k<<<dim3(18,1,256),256,0,stream>>>(qkv, Vt, slens);
        flash_k<<<dim3(5,1,256),256,0,stream>>>(qkv, Vt, ctx, slens);
        gemm_k<128,128,EPI_BF16R><<<dim3(4,141,1),256,0,stream>>>(
            ctx, wot + (size_t)l*262144, tmp16, bo, (long)l*512,
            NTOK_N, 512, 512, 512, 512, 512, 512, 0, flag);
        ln_residual_k<<<NTOK_N,256,0,stream>>>(tmp16, hidf, hidb, l1g, l1b, (long)l*512,
                                               hidb, 0, flag);
        gemm_k<128,128,EPI_GELU><<<dim3(16,141,1),256,0,stream>>>(
            hidb, wit + (size_t)l*1048576, ffb, bi, (long)l*2048,
            NTOK_N, 2048, 512, 512, 512, 2048, 2048, 0, flag);
        gemm_k<128,128,EPI_BF16R><<<dim3(4,141,1),256,0,stream>>>(
            ffb, wft + (size_t)l*1048576, tmp16, bfv, (long)l*512,
            NTOK_N, 512, 2048, 2048, 2048, 512, 512, 0, flag);
        ln_residual_k<<<NTOK_N,256,0,stream>>>(tmp16, hidf, hidb, l2g, l2b, (long)l*512,
                                               (l == NL_N-1) ? d_out : (void*)hidb,
                                               (l == NL_N-1) ? 1 : 0, flag);
    }
}

// Round 4
// 1628.401 us; speedup vs baseline: 1.1728x; 1.0454x over previous
//
#include <hip/hip_runtime.h>
#include <hip/hip_bf16.h>
#include <math.h>

using bf16 = __hip_bfloat16;
typedef __attribute__((ext_vector_type(4))) float f32x4;
typedef __attribute__((ext_vector_type(8))) short short8;

#define B_N 32
#define S_N 512
#define T_N 50
#define H_N 8
#define NL_N 4
#define VB_N 30000
#define VBP_N 30016          // VB padded to mult of 64
#define ST_N 562
#define STP_N 576
#define NTOK_N (B_N*ST_N)   // 17984
#define WCH_N 16             // softmax_wdec column chunks
#define WCW_N 1875           // 30000/16

__device__ __forceinline__ float b2f(bf16 x){ return __bfloat162float(x); }
__device__ __forceinline__ bf16  f2b(float x){ return __float2bfloat16(x); }
// flag-aware raw-input load: f==1 -> buffer is float32, else bf16
__device__ __forceinline__ float ldw(const void* p, long i, int f){
    return f ? ((const float*)p)[i] : __bfloat162float(((const bf16*)p)[i]);
}

// GELU with A&S 7.1.26 erf (|eps| <= 1.5e-7): ~10 VALU + 1 exp vs libm erff's ~40.
__device__ __forceinline__ float gelu_f(float x){
    float z = fabsf(x) * 0.70710678118654752f;
    float t = __builtin_amdgcn_rcpf(__builtin_fmaf(0.3275911f, z, 1.f));
    float p = t*(0.254829592f + t*(-0.284496736f + t*(1.421413741f + t*(-1.453152027f + t*1.061405429f))));
    float er = 1.f - p*__expf(-z*z);
    return 0.5f*x*(1.f + copysignf(er, x));
}

__device__ __forceinline__ void load_lds16(const void* g, void* l){
    __builtin_amdgcn_global_load_lds((const __attribute__((address_space(1))) void*)g,
                                     (__attribute__((address_space(3))) void*)l, 16, 0, 0);
}

// XCD-aware bijective block swizzle (m204): consecutive flat ids round-robin
// over 8 XCDs in hardware; this remap hands each XCD a CONTIGUOUS chunk of
// the flat id space so blocks sharing operand panels land in the same L2.
__device__ __forceinline__ int xcd_swizzle(int flat, int nwg){
    int xcd = flat & 7, rest = flat >> 3;
    int q = nwg >> 3, r = nwg & 7;
    return (xcd < r ? xcd*(q+1) : r*(q+1) + (xcd-r)*q) + rest;
}

__device__ __forceinline__ float block_reduce_max(float v, float* red, int t){
    for (int o=32;o>0;o>>=1) v = fmaxf(v, __shfl_down(v,o,64));
    int w=t>>6, lane=t&63;
    if (lane==0) red[w]=v;
    __syncthreads();
    return fmaxf(fmaxf(red[0],red[1]),fmaxf(red[2],red[3]));
}
__device__ __forceinline__ float block_reduce_sum(float v, float* red, int t){
    for (int o=32;o>0;o>>=1) v += __shfl_down(v,o,64);
    int w=t>>6, lane=t&63;
    if (lane==0) red[w]=v;
    __syncthreads();
    return red[0]+red[1]+red[2]+red[3];
}

// ---------------- dtype detector ----------------
__global__ __launch_bounds__(256) void detect_k(const unsigned int* __restrict__ w, int* flag)
{
    int t = threadIdx.x;
    float s = 0.f;
    for (int i=t;i<4096;i+=256){ int e = (w[i]>>7)&0xFF; s += fabsf((float)e - 120.f); }
    __shared__ float red[4];
    for (int o=32;o>0;o>>=1) s += __shfl_down(s,o,64);
    int wv=t>>6, lane=t&63;
    if (lane==0) red[wv]=s;
    __syncthreads();
    if (t==0) flag[0] = ((red[0]+red[1]+red[2]+red[3]) * (1.f/4096.f) > 20.f) ? 1 : 0;
}

__global__ void zero_u32_k(unsigned int* p, long n){
    long i = (long)blockIdx.x*256 + threadIdx.x;
    if (i < n) p[i] = 0u;
}

// ---------------- topic memory: parallel W_dec softmax ----------------
__global__ __launch_bounds__(256) void wd_partmax_k(
    const void* __restrict__ Wd, const void* __restrict__ bd,
    float* __restrict__ pmax, const int* __restrict__ flagp)
{
    const int isf = *flagp;
    int ch = blockIdx.x, r = blockIdx.y, t = threadIdx.x;
    int c0 = ch*WCW_N, c1 = c0 + WCW_N;
    __shared__ float red[4];
    float mx = -1e30f;
    for (int c=c0+t;c<c1;c+=256) mx = fmaxf(mx, ldw(Wd,(long)r*VB_N+c,isf) + ldw(bd,c,isf));
    mx = block_reduce_max(mx, red, t);
    if (t==0) pmax[r*WCH_N + ch] = mx;
}

__global__ __launch_bounds__(256) void wd_partsum_k(
    const void* __restrict__ Wd, const void* __restrict__ bd,
    const float* __restrict__ pmax, float* __restrict__ psum, const int* __restrict__ flagp)
{
    const int isf = *flagp;
    int ch = blockIdx.x, r = blockIdx.y, t = threadIdx.x;
    float mx = -1e30f;
    #pragma unroll
    for (int i=0;i<WCH_N;i++) mx = fmaxf(mx, pmax[r*WCH_N+i]);
    int c0 = ch*WCW_N, c1 = c0 + WCW_N;
    __shared__ float red[4];
    float sm = 0.f;
    for (int c=c0+t;c<c1;c+=256) sm += __expf(ldw(Wd,(long)r*VB_N+c,isf) + ldw(bd,c,isf) - mx);
    sm = block_reduce_sum(sm, red, t);
    if (t==0) psum[r*WCH_N + ch] = sm;
}

__global__ __launch_bounds__(256) void wd_write_k(
    const void* __restrict__ Wd, const void* __restrict__ bd,
    const float* __restrict__ pmax, const float* __restrict__ psum,
    bf16* __restrict__ wdb, const int* __restrict__ flagp)
{
    const int isf = *flagp;
    int ch = blockIdx.x, r = blockIdx.y, t = threadIdx.x;
    float mx = -1e30f, sm = 0.f;
    #pragma unroll
    for (int i=0;i<WCH_N;i++){ mx = fmaxf(mx, pmax[r*WCH_N+i]); sm += psum[r*WCH_N+i]; }
    float inv = 1.f/sm;
    int c0 = ch*WCW_N, c1 = c0 + WCW_N;
    for (int c=c0+t;c<c1;c+=256)
        wdb[(long)r*VBP_N + c] = f2b(__expf(ldw(Wd,(long)r*VB_N+c,isf) + ldw(bd,c,isf) - mx)*inv);
}

// hrel[64][1024] bf16 = relu(hmem + b1), rows >= T_N zeroed
__global__ __launch_bounds__(256) void relu_bias_k(
    const float* __restrict__ hmem, const void* __restrict__ b1,
    bf16* __restrict__ hrel, const int* __restrict__ flagp)
{
    const int isf = *flagp;
    int r = blockIdx.x, t = threadIdx.x;
    for (int c=t;c<1024;c+=256){
        float v = (r < T_N) ? fmaxf(hmem[r*1024+c] + ldw(b1,c,isf), 0.f) : 0.f;
        hrel[r*1024+c] = f2b(v);
    }
}

// plain LN over 50 rows of fcout[64][512] (bias b2 already added in GEMM epilogue)
__global__ __launch_bounds__(256) void ln_topic_k(
    const float* __restrict__ fcout,
    const void* __restrict__ lg, const void* __restrict__ lb,
    float* __restrict__ tmf, bf16* __restrict__ tmb, const int* __restrict__ flagp)
{
    const int isf = *flagp;
    int r = blockIdx.x, t = threadIdx.x;
    float a0 = fcout[r*512+t], a1 = fcout[r*512+t+256];
    __shared__ float red[4];
    float mean = block_reduce_sum(a0+a1, red, t) * (1.f/512.f);
    float d0=a0-mean, d1=a1-mean;
    __syncthreads();
    float var = block_reduce_sum(d0*d0+d1*d1, red, t) * (1.f/512.f);
    float rstd = rsqrtf(var + 1e-12f);
    float o0 = d0*rstd*ldw(lg,t,isf) + ldw(lb,t,isf);
    float o1 = d1*rstd*ldw(lg,t+256,isf) + ldw(lb,t+256,isf);
    tmf[r*512+t]=o0; tmf[r*512+t+256]=o1;
    tmb[r*512+t]=f2b(o0); tmb[r*512+t+256]=f2b(o1);
}

// ---------------- embedding + ragged insert ----------------
__global__ __launch_bounds__(256) void embed_insert_k(
    const int* __restrict__ ids, const int* __restrict__ lens,
    const void* __restrict__ embed, const float* __restrict__ tmf,
    const bf16* __restrict__ tmb, float* __restrict__ hf, bf16* __restrict__ hb,
    const int* __restrict__ flagp)
{
    const int isf = *flagp;
    int j = blockIdx.x, b = blockIdx.y, t = threadIdx.x;
    int L = lens[b]; L = L<1?1:(L>S_N?S_N:L);
    long orow = ((long)b*ST_N + j)*512;
    if (j >= L && j < L + T_N) {
        int m = j - L;
        for (int c=t;c<512;c+=256){ float v = tmf[m*512+c]; hf[orow+c]=v; hb[orow+c]=tmb[m*512+c]; }
    } else {
        int sj = (j < L) ? j : j - T_N;   // in [0, 511]
        int id = ids[b*S_N + sj];
        for (int c=t;c<512;c+=256){ float e = ldw(embed,(long)id*512+c,isf); hf[orow+c]=e; hb[orow+c]=f2b(e); }
    }
}

// ---------------- weight prep ----------------
// dst[z*dstride + (n0+n)*R + (k0+k)] = src[z*sstride + min(k0+k,Ksrc-1)*C + (n0+n)]
__global__ __launch_bounds__(256) void transpose_k(
    const void* __restrict__ src, bf16* __restrict__ dst,
    int R, int C, long sstride, long dstride, int Ksrc, const int* __restrict__ flagp)
{
    const int isf = *flagp;
    __shared__ bf16 tile[32][33];
    int n0 = blockIdx.x * 32, k0 = blockIdx.y * 32, z = blockIdx.z;
    int t = threadIdx.x;
    int nl = t & 31, kb = t >> 5;
    #pragma unroll
    for (int i=0;i<4;i++) {
        int k = k0 + kb + i*8; k = k < Ksrc ? k : Ksrc-1;
        tile[kb+i*8][nl] = f2b(ldw(src, z*sstride + (long)k*C + n0+nl, isf));
    }
    __syncthreads();
    int kl = t & 31, nb = t >> 5;
    #pragma unroll
    for (int i=0;i<4;i++) {
        int n = nb + i*8;
        dst[z*dstride + (long)(n0+n)*R + k0+kl] = tile[kl][n];
    }
}

__global__ void concat_bias_k(const void* bq, const void* bk, const void* bv, bf16* out,
                              const int* __restrict__ flagp){
    const int isf = *flagp;
    int i = blockIdx.x*256 + threadIdx.x;
    if (i >= NL_N*1536) return;
    int l = i/1536, n = i%1536;
    float v = (n<512) ? ldw(bq,l*512+n,isf) : (n<1024 ? ldw(bk,l*512+n-512,isf) : ldw(bv,l*512+n-1024,isf));
    out[i] = f2b(v);
}

// Vt[z][n][k]: n = head dim (64), k = key (576, zero pad k>=562); z = b*8+h over all 256
// Early-exit: flash only reads k-tiles < ceil((L+T)/64), skip blocks beyond that.
__global__ __launch_bounds__(256) void transpose_v_k(
    const bf16* __restrict__ qkv, bf16* __restrict__ Vt, const int* __restrict__ slens)
{
    __shared__ bf16 tl[64*33];
    int k0 = blockIdx.x * 32, z = blockIdx.z;
    int b = z >> 3, h = z & 7;
    int L = slens[b]; L = L<1?1:(L>S_N?S_N:L);
    int kmax = ((L + T_N + 63) >> 6) << 6;   // active k region rounded to 64
    if (k0 >= kmax) return;
    int t = threadIdx.x;
    int n = t & 63, kb = t >> 6;
    #pragma unroll
    for (int i=0;i<8;i++) {
        int kl = kb + 4*i;
        int kg = k0 + kl;
        bf16 v = (kg < ST_N) ? qkv[((long)(b*ST_N + kg))*1536 + 1024 + h*64 + n] : f2b(0.f);
        tl[n*33 + kl] = v;
    }
    __syncthreads();
    int kk = t & 31, nb = t >> 5;
    #pragma unroll
    for (int i=0;i<8;i++) {
        int nn = nb + 8*i;
        Vt[((long)z*64 + nn)*STP_N + k0 + kk] = tl[nn*33 + kk];
    }
}

// ---------------- MFMA GEMM: C = A[M,K] @ Bt[N,K]^T ----------------
// BK=64 (128 B rows, full 32-bank span) with XOR-8 chunk swizzle:
// LDS chunk p of row r holds global chunk p^(r&7); per 16-lane phase the 8
// chunk positions are hit exactly 2x -> 2-way (free, m136). K must be mult of 64.
// XCD chunk swizzle on the block grid: x-fast flat ids -> contiguous per-XCD
// ranges, so the 16ish column-tile blocks sharing an A row-panel hit one L2.
// Epilogue: per-thread cols are only NI distinct -> bias hoisted to NI regs;
// GELU uses the fast-erf poly (gelu_f) instead of libm erff.
constexpr int EPI_BF16=0, EPI_F32=1, EPI_GELU=2, EPI_ATOMIC=3, EPI_BF16R=4;

template<int BM, int BN, int MODE>
__global__ __launch_bounds__(256,4) void gemm_k(
    const bf16* __restrict__ Ag, const bf16* __restrict__ Bg, void* __restrict__ Cg,
    const void* __restrict__ bias, long bias_off,
    int M, int N, int K, int lda, int ldb, int ldc, int Nst, int kch,
    const int* __restrict__ flagp)
{
    const int isf = *flagp;
    __shared__ __align__(16) bf16 lA[BM*64];
    __shared__ __align__(16) bf16 lB[BN*64];
    const int tid = threadIdx.x;
    const int nwg = gridDim.x * gridDim.y;
    const int flat = blockIdx.y * gridDim.x + blockIdx.x;
    const int swz = xcd_swizzle(flat, nwg);
    const int tile_m = (swz / gridDim.x) * BM;
    const int tile_n = (swz % gridDim.x) * BN;

    bf16*  C16 = (bf16*)Cg;
    float* C32 = (float*)Cg;

    constexpr int WM = BM/2, WN = BN/2, MI = WM/16, NI = WN/16;
    const int w = tid>>6, lane = tid&63;
    const int wm = w>>1, wn = w&1;
    const int quad = lane>>4, lrow = lane&15;

    f32x4 zero = {0.f,0.f,0.f,0.f};
    f32x4 acc[MI][NI];
    #pragma unroll
    for (int i=0;i<MI;i++)
        #pragma unroll
        for (int j=0;j<NI;j++) acc[i][j] = zero;

    int ks = 0, ke = K;
    if (kch > 0) { ks = blockIdx.z * kch; ke = ks + kch; if (ke > K) ke = K; }

    for (int k0=ks;k0<ke;k0+=64) {
        __syncthreads();
        #pragma unroll
        for (int r=0;r<BM/32;r++) {
            int e = r*256 + tid;             // [0, BM*8)
            int row = e>>3, c8 = (e&7) ^ (row&7);
            int gr = tile_m + row; gr = gr < M ? gr : M-1;
            load_lds16(Ag + (long)gr*lda + k0 + c8*8, &lA[e*8]);
        }
        #pragma unroll
        for (int r=0;r<BN/32;r++) {
            int e = r*256 + tid;
            int row = e>>3, c8 = (e&7) ^ (row&7);
            int gr = tile_n + row; gr = gr < N ? gr : N-1;
            load_lds16(Bg + (long)gr*ldb + k0 + c8*8, &lB[e*8]);
        }
        __syncthreads();
        #pragma unroll
        for (int kc=0;kc<2;kc++){
            short8 afr[MI], bfr[NI];
            #pragma unroll
            for (int i=0;i<MI;i++){
                int row = wm*WM + i*16 + lrow;
                afr[i] = *(const short8*)&lA[row*64 + (((kc*4+quad) ^ (row&7))<<3)];
            }
            #pragma unroll
            for (int j=0;j<NI;j++){
                int row = wn*WN + j*16 + lrow;
                bfr[j] = *(const short8*)&lB[row*64 + (((kc*4+quad) ^ (row&7))<<3)];
            }
            #pragma unroll
            for (int i=0;i<MI;i++)
                #pragma unroll
                for (int j=0;j<NI;j++)
                    acc[i][j] = __builtin_amdgcn_mfma_f32_16x16x32_bf16(afr[i], bfr[j], acc[i][j], 0, 0, 0);
        }
    }

    // bias hoist: only NI distinct columns per thread
    float bcol[NI];
    #pragma unroll
    for (int j=0;j<NI;j++){
        int col = tile_n + wn*WN + j*16 + lrow;
        if constexpr (MODE == EPI_ATOMIC) { bcol[j] = 0.f; }
        else if constexpr (MODE == EPI_BF16) {
            bcol[j] = (col < Nst) ? b2f(((const bf16*)bias)[bias_off + col]) : 0.f;
        } else {
            bcol[j] = (col < Nst) ? ldw(bias, bias_off + col, isf) : 0.f;
        }
    }

    #pragma unroll
    for (int i=0;i<MI;i++) {
        #pragma unroll
        for (int j=0;j<NI;j++) {
            int col = tile_n + wn*WN + j*16 + lrow;
            if (col >= Nst) continue;
            int rb  = tile_m + wm*WM + i*16 + quad*4;
            #pragma unroll
            for (int r=0;r<4;r++) {
                int row = rb + r;
                if (row >= M) continue;
                float v = acc[i][j][r];
                if constexpr (MODE == EPI_BF16 || MODE == EPI_BF16R) {
                    C16[(long)row*ldc + col] = f2b(v + bcol[j]);
                } else if constexpr (MODE == EPI_F32) {
                    C32[(long)row*ldc + col] = v + bcol[j];
                } else if constexpr (MODE == EPI_GELU) {
                    C16[(long)row*ldc + col] = f2b(gelu_f(v + bcol[j]));
                } else { // EPI_ATOMIC
                    atomicAdd(&C32[(long)row*ldc + col], v);
                }
            }
        }
    }
}

// ---------------- flash attention ----------------
// Early-exit over KV tiles (bit-identical: masked tiles give exp()==0.0f).
// K/V double-buffered: next-K staged after barrier-1 (hides under QK+softmax),
// next-V staged after barrier-2 (hides under PV). LDS 64KB = 2 blocks/CU,
// matching the launch_bounds cap, so occupancy is unchanged.
// XCD swizzle: the 5 q-tiles of one (b,h) share its K/V panels -> one L2.
__global__ __launch_bounds__(256,2) void flash_k(
    const bf16* __restrict__ qkv, const bf16* __restrict__ Vt,
    bf16* __restrict__ ctx, const int* __restrict__ slens)
{
    __shared__ __align__(16) bf16 lQ[128*64];
    __shared__ __align__(16) bf16 lK[2][64*64];
    __shared__ __align__(16) bf16 lV[2][64*64];
    __shared__ __align__(16) bf16 lP[128*64];
    const int nwg = gridDim.x * gridDim.z;
    const int flat = blockIdx.z * gridDim.x + blockIdx.x;
    const int swz = xcd_swizzle(flat, nwg);
    const int z = swz / gridDim.x, b = z>>3, h = z&7;
    const int qt = swz % gridDim.x;
    const int tid = threadIdx.x;
    const int w = tid>>6, lane = tid&63;
    const int quad = lane>>4, l15 = lane&15;
    int L = slens[b]; L = L<1?1:(L>S_N?S_N:L);
    const int lenT = L + T_N;
    const int nkt = (lenT + 63) >> 6;   // active KV tiles (wave-uniform)

    #pragma unroll
    for (int rr=0;rr<4;rr++){
        int ci = rr*256 + tid;
        int row = ci>>3, c8 = (ci&7) ^ (row&7);
        int gr = qt*128 + row; gr = gr < ST_N ? gr : ST_N-1;
        load_lds16(qkv + ((long)(b*ST_N+gr))*1536 + h*64 + c8*8, &lQ[ci*8]);
    }

    auto stage_K = [&](int buf, int kt){
        #pragma unroll
        for (int rr=0;rr<2;rr++){
            int ci = rr*256+tid;
            int row = ci>>3, c8 = (ci&7) ^ (row&7);
            int kr = kt*64+row; kr = kr < ST_N ? kr : ST_N-1;
            load_lds16(qkv + ((long)(b*ST_N+kr))*1536 + 512 + h*64 + c8*8, &lK[buf][ci*8]);
        }
    };
    auto stage_V = [&](int buf, int kt){
        #pragma unroll
        for (int rr=0;rr<2;rr++){
            int ci = rr*256+tid;
            int n = ci>>3, c8 = (ci&7) ^ (n&7);
            load_lds16(Vt + ((long)z*64+n)*STP_N + kt*64 + c8*8, &lV[buf][ci*8]);
        }
    };

    stage_K(0, 0);
    stage_V(0, 0);

    f32x4 zerov = {0.f,0.f,0.f,0.f};
    f32x4 O[2][4];
    float m_i[2][4], l_i[2][4];
    #pragma unroll
    for (int i=0;i<2;i++){
        #pragma unroll
        for (int j=0;j<4;j++) O[i][j] = zerov;
        #pragma unroll
        for (int r=0;r<4;r++){ m_i[i][r]=-1e30f; l_i[i][r]=0.f; }
    }

    for (int kt=0; kt<nkt; kt++){
        const int cur = kt & 1;
        __syncthreads();                         // K[cur],V[cur] ready; lP reads done
        if (kt+1 < nkt) stage_K(cur^1, kt+1);    // overlaps QK + softmax

        f32x4 S[2][4];
        #pragma unroll
        for (int i=0;i<2;i++)
            #pragma unroll
            for (int j=0;j<4;j++) S[i][j] = zerov;
        #pragma unroll
        for (int kc=0;kc<2;kc++){
            short8 aQ[2], bK[4];
            #pragma unroll
            for (int i=0;i<2;i++){
                int row = w*32+i*16+l15;
                aQ[i] = *(const short8*)&lQ[row*64 + (((kc*4+quad) ^ (row&7))<<3)];
            }
            #pragma unroll
            for (int j=0;j<4;j++){
                int row = j*16+l15;
                bK[j] = *(const short8*)&lK[cur][row*64 + (((kc*4+quad) ^ (row&7))<<3)];
            }
            #pragma unroll
            for (int i=0;i<2;i++)
                #pragma unroll
                for (int j=0;j<4;j++)
                    S[i][j] = __builtin_amdgcn_mfma_f32_16x16x32_bf16(aQ[i], bK[j], S[i][j], 0,0,0);
        }

        #pragma unroll
        for (int i=0;i<2;i++){
            #pragma unroll
            for (int r=0;r<4;r++){
                float mx = -1e30f;
                #pragma unroll
                for (int j=0;j<4;j++){
                    int col = kt*64 + j*16 + l15;
                    float s = S[i][j][r]*0.125f + (col < lenT ? 0.f : -10000.f);
                    S[i][j][r] = s;
                    mx = fmaxf(mx, s);
                }
                #pragma unroll
                for (int o=1;o<16;o<<=1) mx = fmaxf(mx, __shfl_xor(mx, o, 64));
                float mn = fmaxf(m_i[i][r], mx);
                float alpha = __expf(m_i[i][r] - mn);
                m_i[i][r] = mn;
                float sm = 0.f;
                #pragma unroll
                for (int j=0;j<4;j++){
                    float pv = __expf(S[i][j][r] - mn);
                    S[i][j][r] = pv;
                    sm += pv;
                }
                #pragma unroll
                for (int o=1;o<16;o<<=1) sm += __shfl_xor(sm, o, 64);
                l_i[i][r] = l_i[i][r]*alpha + sm;
                #pragma unroll
                for (int j=0;j<4;j++) O[i][j][r] *= alpha;
            }
        }

        #pragma unroll
        for (int i=0;i<2;i++)
            #pragma unroll
            for (int j=0;j<4;j++)
                #pragma unroll
                for (int r=0;r<4;r++){
                    int row = w*32 + i*16 + quad*4 + r;
                    int col = j*16 + l15;
                    lP[row*64 + (((col>>3) ^ (row&7))<<3) + (col&7)] = f2b(S[i][j][r]);
                }
        __syncthreads();                         // lP visible
        if (kt+1 < nkt) stage_V(cur^1, kt+1);    // overlaps PV

        #pragma unroll
        for (int kc=0;kc<2;kc++){
            short8 aP[2], bV[4];
            #pragma unroll
            for (int i=0;i<2;i++){
                int row = w*32+i*16+l15;
                aP[i] = *(const short8*)&lP[row*64 + (((kc*4+quad) ^ (row&7))<<3)];
            }
            #pragma unroll
            for (int j=0;j<4;j++){
                int row = j*16+l15;
                bV[j] = *(const short8*)&lV[cur][row*64 + (((kc*4+quad) ^ (row&7))<<3)];
            }
            #pragma unroll
            for (int i=0;i<2;i++)
                #pragma unroll
                for (int j=0;j<4;j++)
                    O[i][j] = __builtin_amdgcn_mfma_f32_16x16x32_bf16(aP[i], bV[j], O[i][j], 0,0,0);
        }
    }

    #pragma unroll
    for (int i=0;i<2;i++)
        #pragma unroll
        for (int j=0;j<4;j++)
            #pragma unroll
            for (int r=0;r<4;r++){
                int row = qt*128 + w*32 + i*16 + quad*4 + r;
                if (row < ST_N)
                    ctx[((long)(b*ST_N+row))*512 + h*64 + j*16 + l15] = f2b(O[i][j][r] / l_i[i][r]);
            }
}

// ---------------- residual + LN (fp32 state + bf16 shadow), bf16 tmp ----------------
__global__ __launch_bounds__(256) void ln_residual_k(
    const bf16* __restrict__ tmp, float* __restrict__ hf, bf16* __restrict__ hb,
    const void* __restrict__ g, const void* __restrict__ bb, long goff,
    void* __restrict__ outp, int is_final, const int* __restrict__ flagp)
{
    const int isf = *flagp;
    const int of32 = is_final && isf;
    long base = (long)blockIdx.x * 512;
    int t = threadIdx.x;
    float v0 = hf[base+t]     + b2f(tmp[base+t]);
    float v1 = hf[base+t+256] + b2f(tmp[base+t+256]);
    __shared__ float red[4];
    float mean = block_reduce_sum(v0+v1, red, t) * (1.f/512.f);
    float d0=v0-mean, d1=v1-mean;
    __syncthreads();
    float var = block_reduce_sum(d0*d0+d1*d1, red, t) * (1.f/512.f);
    float rstd = rsqrtf(var + 1e-12f);
    float o0 = d0*rstd*ldw(g,goff+t,isf) + ldw(bb,goff+t,isf);
    float o1 = d1*rstd*ldw(g,goff+t+256,isf) + ldw(bb,goff+t+256,isf);
    hf[base+t]=o0; hf[base+t+256]=o1;
    hb[base+t]=f2b(o0); hb[base+t+256]=f2b(o1);
    if (of32) {
        ((float*)outp)[base+t]=o0; ((float*)outp)[base+t+256]=o1;
    } else {
        ((bf16*)outp)[base+t]=f2b(o0); ((bf16*)outp)[base+t+256]=f2b(o1);
    }
}

extern "C" void kernel_launch(void* const* d_in, const int* in_sizes, int n_in,
                              void* d_out, int out_size, void* d_ws, size_t ws_size,
                              hipStream_t stream)
{
    (void)in_sizes; (void)n_in; (void)out_size; (void)ws_size;
    const int*  ids   = (const int*) d_in[0];
    const int*  slens = (const int*) d_in[1];
    const void* embed = d_in[2];
    const void* Wdec  = d_in[3];
    const void* bdec  = d_in[4];
    const void* mW1   = d_in[5];
    const void* mb1   = d_in[6];
    const void* mW2   = d_in[7];
    const void* mb2   = d_in[8];
    const void* mlg   = d_in[9];
    const void* mlb   = d_in[10];
    const void* Wq    = d_in[11];
    const void* bq    = d_in[12];
    const void* Wk    = d_in[13];
    const void* bk    = d_in[14];
    const void* Wv    = d_in[15];
    const void* bv    = d_in[16];
    const void* Wo    = d_in[17];
    const void* bo    = d_in[18];
    const void* l1g   = d_in[19];
    const void* l1b   = d_in[20];
    const void* Wi    = d_in[21];
    const void* bi    = d_in[22];
    const void* Wf    = d_in[23];
    const void* bfv   = d_in[24];
    const void* l2g   = d_in[25];
    const void* l2b   = d_in[26];

    char* p = (char*)d_ws;
    auto alloc = [&](size_t bytes)->void* {
        void* r = (void*)p; p += (bytes + 255) & ~(size_t)255; return r; };
    int*   flag  = (int*)  alloc(256);
    float* pmax  = (float*)alloc((size_t)T_N*WCH_N*4);
    float* psum  = (float*)alloc((size_t)T_N*WCH_N*4);
    float* tmf   = (float*)alloc((size_t)T_N*512*4);
    bf16*  tmb   = (bf16*) alloc((size_t)T_N*512*2);
    float* hmem  = (float*)alloc((size_t)64*1024*4);
    bf16*  hrel  = (bf16*) alloc((size_t)64*1024*2);
    float* fcout = (float*)alloc((size_t)64*512*4);
    float* hidf  = (float*)alloc((size_t)NTOK_N*512*4);
    bf16*  hidb  = (bf16*) alloc((size_t)NTOK_N*512*2);
    bf16*  qkvt  = (bf16*) alloc((size_t)NL_N*1536*512*2);
    bf16*  wot   = (bf16*) alloc((size_t)NL_N*512*512*2);
    bf16*  wit   = (bf16*) alloc((size_t)NL_N*2048*512*2);
    bf16*  wft   = (bf16*) alloc((size_t)NL_N*512*2048*2);
    bf16*  bqkv  = (bf16*) alloc((size_t)NL_N*1536*2);
    // R1 union (time-disjoint): prelude [wdb 3.84M | W1t 61.5M | W2t 1M] <-> [qkv 55.25M] <-> [ffb 73.66M]
    char*  R1    = (char*) alloc((size_t)NTOK_N*2048*2);
    bf16*  wdb   = (bf16*)R1;
    bf16*  W1t   = (bf16*)(R1 + (size_t)64*VBP_N*2);
    bf16*  W2t   = (bf16*)(R1 + (size_t)64*VBP_N*2 + (size_t)1024*VBP_N*2);
    bf16*  qkv   = (bf16*)R1;
    bf16*  ffb   = (bf16*)R1;
    // RU2: ctx (18.42M) + [Vt 18.87M <-> tmp16 18.42M]
    bf16*  ctx   = (bf16*) alloc((size_t)NTOK_N*512*2);
    char*  RU2   = (char*) alloc((size_t)NTOK_N*512*4);
    bf16*  Vt    = (bf16*)RU2;
    bf16*  tmp16 = (bf16*)RU2;
    // total ~= 210 MB

    detect_k<<<1,256,0,stream>>>((const unsigned int*)embed, flag);

    // topic memory: parallel softmax -> FC1 (MFMA, K-split atomic) -> relu -> FC2 (MFMA) -> LN
    zero_u32_k<<<((64L*VBP_N/2)+255)/256,256,0,stream>>>((unsigned int*)wdb, 64L*VBP_N/2);
    zero_u32_k<<<((64L*1024)+255)/256,256,0,stream>>>((unsigned int*)hmem, 64L*1024);
    wd_partmax_k<<<dim3(WCH_N,T_N),256,0,stream>>>(Wdec,bdec,pmax,flag);
    wd_partsum_k<<<dim3(WCH_N,T_N),256,0,stream>>>(Wdec,bdec,pmax,psum,flag);
    wd_write_k  <<<dim3(WCH_N,T_N),256,0,stream>>>(Wdec,bdec,pmax,psum,wdb,flag);
    transpose_k<<<dim3(32,VBP_N/32,1),256,0,stream>>>(mW1, W1t, VBP_N, 1024, 0L, 0L, VB_N, flag);
    transpose_k<<<dim3(16,32,1),256,0,stream>>>(mW2, W2t, 1024, 512, 0L, 0L, 1024, flag);
    gemm_k<64,128,EPI_ATOMIC><<<dim3(8,1,32),256,0,stream>>>(
        wdb, W1t, hmem, nullptr, 0,
        64, 1024, VBP_N, VBP_N, VBP_N, 1024, 1024, 960, flag);
    relu_bias_k<<<64,256,0,stream>>>(hmem, mb1, hrel, flag);
    gemm_k<64,128,EPI_F32><<<dim3(4,1,1),256,0,stream>>>(
        hrel, W2t, fcout, mb2, 0,
        64, 512, 1024, 1024, 1024, 512, 512, 0, flag);
    ln_topic_k<<<T_N,256,0,stream>>>(fcout, mlg, mlb, tmf, tmb, flag);
    embed_insert_k<<<dim3(ST_N,B_N),256,0,stream>>>(ids, slens, embed, tmf, tmb, hidf, hidb, flag);

    // weight prep (canonical bf16, [N][K] layouts)
    transpose_k<<<dim3(16,16,NL_N),256,0,stream>>>(Wq, qkvt,          512, 512, 262144L, 786432L, 512, flag);
    transpose_k<<<dim3(16,16,NL_N),256,0,stream>>>(Wk, qkvt+262144,   512, 512, 262144L, 786432L, 512, flag);
    transpose_k<<<dim3(16,16,NL_N),256,0,stream>>>(Wv, qkvt+524288,   512, 512, 262144L, 786432L, 512, flag);
    transpose_k<<<dim3(16,16,NL_N),256,0,stream>>>(Wo, wot,           512, 512, 262144L, 262144L, 512, flag);
    transpose_k<<<dim3(64,16,NL_N),256,0,stream>>>(Wi, wit,           512, 2048, 1048576L, 1048576L, 512, flag);
    transpose_k<<<dim3(16,64,NL_N),256,0,stream>>>(Wf, wft,           2048, 512, 1048576L, 1048576L, 2048, flag);
    concat_bias_k<<<(NL_N*1536+255)/256,256,0,stream>>>(bq,bk,bv,bqkv,flag);

    for (int l=0;l<NL_N;l++) {
        gemm_k<128,128,EPI_BF16><<<dim3(12,141,1),256,0,stream>>>(
            hidb, qkvt + (size_t)l*786432, qkv, bqkv, (long)l*1536,
            NTOK_N, 1536, 512, 512, 512, 1536, 1536, 0, flag);
        transpose_v_k<<<dim3(18,1,256),256,0,stream>>>(qkv, Vt, slens);
        flash_k<<<dim3(5,1,256),256,0,stream>>>(qkv, Vt, ctx, slens);
        gemm_k<128,128,EPI_BF16R><<<dim3(4,141,1),256,0,stream>>>(
            ctx, wot + (size_t)l*262144, tmp16, bo, (long)l*512,
            NTOK_N, 512, 512, 512, 512, 512, 512, 0, flag);
        ln_residual_k<<<NTOK_N,256,0,stream>>>(tmp16, hidf, hidb, l1g, l1b, (long)l*512,
                                               hidb, 0, flag);
        gemm_k<128,128,EPI_GELU><<<dim3(16,141,1),256,0,stream>>>(
            hidb, wit + (size_t)l*1048576, ffb, bi, (long)l*2048,
            NTOK_N, 2048, 512, 512, 512, 2048, 2048, 0, flag);
        gemm_k<128,128,EPI_BF16R><<<dim3(4,141,1),256,0,stream>>>(
            ffb, wft + (size_t)l*1048576, tmp16, bfv, (long)l*512,
            NTOK_N, 512, 2048, 2048, 2048, 512, 512, 0, flag);
        ln_residual_k<<<NTOK_N,256,0,stream>>>(tmp16, hidf, hidb, l2g, l2b, (long)l*512,
                                               (l == NL_N-1) ? d_out : (void*)hidb,
                                               (l == NL_N-1) ? 1 : 0, flag);
    }
}

// Round 5
// 1578.791 us; speedup vs baseline: 1.2096x; 1.0314x over previous
//
#include <hip/hip_runtime.h>
#include <hip/hip_bf16.h>
#include <math.h>

using bf16 = __hip_bfloat16;
typedef __attribute__((ext_vector_type(4))) float f32x4;
typedef __attribute__((ext_vector_type(8))) short short8;

#define B_N 32
#define S_N 512
#define T_N 50
#define H_N 8
#define NL_N 4
#define VB_N 30000
#define VBP_N 30016          // VB padded to mult of 64
#define ST_N 562
#define STP_N 576
#define NTOK_N (B_N*ST_N)   // 17984
#define WCH_N 16             // softmax_wdec column chunks
#define WCW_N 1875           // 30000/16

__device__ __forceinline__ float b2f(bf16 x){ return __bfloat162float(x); }
__device__ __forceinline__ bf16  f2b(float x){ return __float2bfloat16(x); }
// flag-aware raw-input load: f==1 -> buffer is float32, else bf16
__device__ __forceinline__ float ldw(const void* p, long i, int f){
    return f ? ((const float*)p)[i] : __bfloat162float(((const bf16*)p)[i]);
}

// GELU with A&S 7.1.26 erf (|eps| <= 1.5e-7): ~10 VALU + 1 exp vs libm erff's ~40.
__device__ __forceinline__ float gelu_f(float x){
    float z = fabsf(x) * 0.70710678118654752f;
    float t = __builtin_amdgcn_rcpf(__builtin_fmaf(0.3275911f, z, 1.f));
    float p = t*(0.254829592f + t*(-0.284496736f + t*(1.421413741f + t*(-1.453152027f + t*1.061405429f))));
    float er = 1.f - p*__expf(-z*z);
    return 0.5f*x*(1.f + copysignf(er, x));
}

__device__ __forceinline__ void load_lds16(const void* g, void* l){
    __builtin_amdgcn_global_load_lds((const __attribute__((address_space(1))) void*)g,
                                     (__attribute__((address_space(3))) void*)l, 16, 0, 0);
}

// XCD-aware bijective block swizzle (m204): consecutive flat ids round-robin
// over 8 XCDs in hardware; this remap hands each XCD a CONTIGUOUS chunk of
// the flat id space so blocks sharing operand panels land in the same L2.
__device__ __forceinline__ int xcd_swizzle(int flat, int nwg){
    int xcd = flat & 7, rest = flat >> 3;
    int q = nwg >> 3, r = nwg & 7;
    return (xcd < r ? xcd*(q+1) : r*(q+1) + (xcd-r)*q) + rest;
}

__device__ __forceinline__ float block_reduce_max(float v, float* red, int t){
    for (int o=32;o>0;o>>=1) v = fmaxf(v, __shfl_down(v,o,64));
    int w=t>>6, lane=t&63;
    if (lane==0) red[w]=v;
    __syncthreads();
    return fmaxf(fmaxf(red[0],red[1]),fmaxf(red[2],red[3]));
}
__device__ __forceinline__ float block_reduce_sum(float v, float* red, int t){
    for (int o=32;o>0;o>>=1) v += __shfl_down(v,o,64);
    int w=t>>6, lane=t&63;
    if (lane==0) red[w]=v;
    __syncthreads();
    return red[0]+red[1]+red[2]+red[3];
}

// ---------------- dtype detector ----------------
__global__ __launch_bounds__(256) void detect_k(const unsigned int* __restrict__ w, int* flag)
{
    int t = threadIdx.x;
    float s = 0.f;
    for (int i=t;i<4096;i+=256){ int e = (w[i]>>7)&0xFF; s += fabsf((float)e - 120.f); }
    __shared__ float red[4];
    for (int o=32;o>0;o>>=1) s += __shfl_down(s,o,64);
    int wv=t>>6, lane=t&63;
    if (lane==0) red[wv]=s;
    __syncthreads();
    if (t==0) flag[0] = ((red[0]+red[1]+red[2]+red[3]) * (1.f/4096.f) > 20.f) ? 1 : 0;
}

__global__ void zero_u32_k(unsigned int* p, long n){
    long i = (long)blockIdx.x*256 + threadIdx.x;
    if (i < n) p[i] = 0u;
}

// ---------------- topic memory: parallel W_dec softmax ----------------
__global__ __launch_bounds__(256) void wd_partmax_k(
    const void* __restrict__ Wd, const void* __restrict__ bd,
    float* __restrict__ pmax, const int* __restrict__ flagp)
{
    const int isf = *flagp;
    int ch = blockIdx.x, r = blockIdx.y, t = threadIdx.x;
    int c0 = ch*WCW_N, c1 = c0 + WCW_N;
    __shared__ float red[4];
    float mx = -1e30f;
    for (int c=c0+t;c<c1;c+=256) mx = fmaxf(mx, ldw(Wd,(long)r*VB_N+c,isf) + ldw(bd,c,isf));
    mx = block_reduce_max(mx, red, t);
    if (t==0) pmax[r*WCH_N + ch] = mx;
}

__global__ __launch_bounds__(256) void wd_partsum_k(
    const void* __restrict__ Wd, const void* __restrict__ bd,
    const float* __restrict__ pmax, float* __restrict__ psum, const int* __restrict__ flagp)
{
    const int isf = *flagp;
    int ch = blockIdx.x, r = blockIdx.y, t = threadIdx.x;
    float mx = -1e30f;
    #pragma unroll
    for (int i=0;i<WCH_N;i++) mx = fmaxf(mx, pmax[r*WCH_N+i]);
    int c0 = ch*WCW_N, c1 = c0 + WCW_N;
    __shared__ float red[4];
    float sm = 0.f;
    for (int c=c0+t;c<c1;c+=256) sm += __expf(ldw(Wd,(long)r*VB_N+c,isf) + ldw(bd,c,isf) - mx);
    sm = block_reduce_sum(sm, red, t);
    if (t==0) psum[r*WCH_N + ch] = sm;
}

__global__ __launch_bounds__(256) void wd_write_k(
    const void* __restrict__ Wd, const void* __restrict__ bd,
    const float* __restrict__ pmax, const float* __restrict__ psum,
    bf16* __restrict__ wdb, const int* __restrict__ flagp)
{
    const int isf = *flagp;
    int ch = blockIdx.x, r = blockIdx.y, t = threadIdx.x;
    float mx = -1e30f, sm = 0.f;
    #pragma unroll
    for (int i=0;i<WCH_N;i++){ mx = fmaxf(mx, pmax[r*WCH_N+i]); sm += psum[r*WCH_N+i]; }
    float inv = 1.f/sm;
    int c0 = ch*WCW_N, c1 = c0 + WCW_N;
    for (int c=c0+t;c<c1;c+=256)
        wdb[(long)r*VBP_N + c] = f2b(__expf(ldw(Wd,(long)r*VB_N+c,isf) + ldw(bd,c,isf) - mx)*inv);
}

// hrel[64][1024] bf16 = relu(hmem + b1), rows >= T_N zeroed
__global__ __launch_bounds__(256) void relu_bias_k(
    const float* __restrict__ hmem, const void* __restrict__ b1,
    bf16* __restrict__ hrel, const int* __restrict__ flagp)
{
    const int isf = *flagp;
    int r = blockIdx.x, t = threadIdx.x;
    for (int c=t;c<1024;c+=256){
        float v = (r < T_N) ? fmaxf(hmem[r*1024+c] + ldw(b1,c,isf), 0.f) : 0.f;
        hrel[r*1024+c] = f2b(v);
    }
}

// plain LN over 50 rows of fcout[64][512] (bias b2 already added in GEMM epilogue)
__global__ __launch_bounds__(256) void ln_topic_k(
    const float* __restrict__ fcout,
    const void* __restrict__ lg, const void* __restrict__ lb,
    float* __restrict__ tmf, bf16* __restrict__ tmb, const int* __restrict__ flagp)
{
    const int isf = *flagp;
    int r = blockIdx.x, t = threadIdx.x;
    float a0 = fcout[r*512+t], a1 = fcout[r*512+t+256];
    __shared__ float red[4];
    float mean = block_reduce_sum(a0+a1, red, t) * (1.f/512.f);
    float d0=a0-mean, d1=a1-mean;
    __syncthreads();
    float var = block_reduce_sum(d0*d0+d1*d1, red, t) * (1.f/512.f);
    float rstd = rsqrtf(var + 1e-12f);
    float o0 = d0*rstd*ldw(lg,t,isf) + ldw(lb,t,isf);
    float o1 = d1*rstd*ldw(lg,t+256,isf) + ldw(lb,t+256,isf);
    tmf[r*512+t]=o0; tmf[r*512+t+256]=o1;
    tmb[r*512+t]=f2b(o0); tmb[r*512+t+256]=f2b(o1);
}

// ---------------- embedding + ragged insert ----------------
__global__ __launch_bounds__(256) void embed_insert_k(
    const int* __restrict__ ids, const int* __restrict__ lens,
    const void* __restrict__ embed, const float* __restrict__ tmf,
    const bf16* __restrict__ tmb, float* __restrict__ hf, bf16* __restrict__ hb,
    const int* __restrict__ flagp)
{
    const int isf = *flagp;
    int j = blockIdx.x, b = blockIdx.y, t = threadIdx.x;
    int L = lens[b]; L = L<1?1:(L>S_N?S_N:L);
    long orow = ((long)b*ST_N + j)*512;
    if (j >= L && j < L + T_N) {
        int m = j - L;
        for (int c=t;c<512;c+=256){ float v = tmf[m*512+c]; hf[orow+c]=v; hb[orow+c]=tmb[m*512+c]; }
    } else {
        int sj = (j < L) ? j : j - T_N;   // in [0, 511]
        int id = ids[b*S_N + sj];
        for (int c=t;c<512;c+=256){ float e = ldw(embed,(long)id*512+c,isf); hf[orow+c]=e; hb[orow+c]=f2b(e); }
    }
}

// ---------------- weight prep ----------------
// dst[z*dstride + (n0+n)*R + (k0+k)] = src[z*sstride + min(k0+k,Ksrc-1)*C + (n0+n)]
__global__ __launch_bounds__(256) void transpose_k(
    const void* __restrict__ src, bf16* __restrict__ dst,
    int R, int C, long sstride, long dstride, int Ksrc, const int* __restrict__ flagp)
{
    const int isf = *flagp;
    __shared__ bf16 tile[32][33];
    int n0 = blockIdx.x * 32, k0 = blockIdx.y * 32, z = blockIdx.z;
    int t = threadIdx.x;
    int nl = t & 31, kb = t >> 5;
    #pragma unroll
    for (int i=0;i<4;i++) {
        int k = k0 + kb + i*8; k = k < Ksrc ? k : Ksrc-1;
        tile[kb+i*8][nl] = f2b(ldw(src, z*sstride + (long)k*C + n0+nl, isf));
    }
    __syncthreads();
    int kl = t & 31, nb = t >> 5;
    #pragma unroll
    for (int i=0;i<4;i++) {
        int n = nb + i*8;
        dst[z*dstride + (long)(n0+n)*R + k0+kl] = tile[kl][n];
    }
}

__global__ void concat_bias_k(const void* bq, const void* bk, const void* bv, bf16* out,
                              const int* __restrict__ flagp){
    const int isf = *flagp;
    int i = blockIdx.x*256 + threadIdx.x;
    if (i >= NL_N*1536) return;
    int l = i/1536, n = i%1536;
    float v = (n<512) ? ldw(bq,l*512+n,isf) : (n<1024 ? ldw(bk,l*512+n-512,isf) : ldw(bv,l*512+n-1024,isf));
    out[i] = f2b(v);
}

// Vt[z][n][k]: n = head dim (64), k = key (576, zero pad k>=562); z = b*8+h over all 256
// Early-exit: flash only reads k-tiles < ceil((L+T)/64), skip blocks beyond that.
__global__ __launch_bounds__(256) void transpose_v_k(
    const bf16* __restrict__ qkv, bf16* __restrict__ Vt, const int* __restrict__ slens)
{
    __shared__ bf16 tl[64*33];
    int k0 = blockIdx.x * 32, z = blockIdx.z;
    int b = z >> 3, h = z & 7;
    int L = slens[b]; L = L<1?1:(L>S_N?S_N:L);
    int kmax = ((L + T_N + 63) >> 6) << 6;   // active k region rounded to 64
    if (k0 >= kmax) return;
    int t = threadIdx.x;
    int n = t & 63, kb = t >> 6;
    #pragma unroll
    for (int i=0;i<8;i++) {
        int kl = kb + 4*i;
        int kg = k0 + kl;
        bf16 v = (kg < ST_N) ? qkv[((long)(b*ST_N + kg))*1536 + 1024 + h*64 + n] : f2b(0.f);
        tl[n*33 + kl] = v;
    }
    __syncthreads();
    int kk = t & 31, nb = t >> 5;
    #pragma unroll
    for (int i=0;i<8;i++) {
        int nn = nb + 8*i;
        Vt[((long)z*64 + nn)*STP_N + k0 + kk] = tl[nn*33 + kk];
    }
}

// ---------------- MFMA GEMM: C = A[M,K] @ Bt[N,K]^T ----------------
// BK=64 (128 B rows, full 32-bank span) with XOR-8 chunk swizzle:
// LDS chunk p of row r holds global chunk p^(r&7); per 16-lane phase the 8
// chunk positions are hit exactly 2x -> 2-way (free, m136). K must be mult of 64.
// XCD chunk swizzle on the block grid: x-fast flat ids -> contiguous per-XCD
// ranges, so the 16ish column-tile blocks sharing an A row-panel hit one L2.
// Epilogue: per-thread cols are only NI distinct -> bias hoisted to NI regs;
// GELU uses the fast-erf poly (gelu_f) instead of libm erff.
constexpr int EPI_BF16=0, EPI_F32=1, EPI_GELU=2, EPI_ATOMIC=3, EPI_BF16R=4;

template<int BM, int BN, int MODE>
__global__ __launch_bounds__(256,4) void gemm_k(
    const bf16* __restrict__ Ag, const bf16* __restrict__ Bg, void* __restrict__ Cg,
    const void* __restrict__ bias, long bias_off,
    int M, int N, int K, int lda, int ldb, int ldc, int Nst, int kch,
    const int* __restrict__ flagp)
{
    const int isf = *flagp;
    __shared__ __align__(16) bf16 lA[BM*64];
    __shared__ __align__(16) bf16 lB[BN*64];
    const int tid = threadIdx.x;
    const int nwg = gridDim.x * gridDim.y;
    const int flat = blockIdx.y * gridDim.x + blockIdx.x;
    const int swz = xcd_swizzle(flat, nwg);
    const int tile_m = (swz / gridDim.x) * BM;
    const int tile_n = (swz % gridDim.x) * BN;

    bf16*  C16 = (bf16*)Cg;
    float* C32 = (float*)Cg;

    constexpr int WM = BM/2, WN = BN/2, MI = WM/16, NI = WN/16;
    const int w = tid>>6, lane = tid&63;
    const int wm = w>>1, wn = w&1;
    const int quad = lane>>4, lrow = lane&15;

    f32x4 zero = {0.f,0.f,0.f,0.f};
    f32x4 acc[MI][NI];
    #pragma unroll
    for (int i=0;i<MI;i++)
        #pragma unroll
        for (int j=0;j<NI;j++) acc[i][j] = zero;

    int ks = 0, ke = K;
    if (kch > 0) { ks = blockIdx.z * kch; ke = ks + kch; if (ke > K) ke = K; }

    for (int k0=ks;k0<ke;k0+=64) {
        __syncthreads();
        #pragma unroll
        for (int r=0;r<BM/32;r++) {
            int e = r*256 + tid;             // [0, BM*8)
            int row = e>>3, c8 = (e&7) ^ (row&7);
            int gr = tile_m + row; gr = gr < M ? gr : M-1;
            load_lds16(Ag + (long)gr*lda + k0 + c8*8, &lA[e*8]);
        }
        #pragma unroll
        for (int r=0;r<BN/32;r++) {
            int e = r*256 + tid;
            int row = e>>3, c8 = (e&7) ^ (row&7);
            int gr = tile_n + row; gr = gr < N ? gr : N-1;
            load_lds16(Bg + (long)gr*ldb + k0 + c8*8, &lB[e*8]);
        }
        __syncthreads();
        #pragma unroll
        for (int kc=0;kc<2;kc++){
            short8 afr[MI], bfr[NI];
            #pragma unroll
            for (int i=0;i<MI;i++){
                int row = wm*WM + i*16 + lrow;
                afr[i] = *(const short8*)&lA[row*64 + (((kc*4+quad) ^ (row&7))<<3)];
            }
            #pragma unroll
            for (int j=0;j<NI;j++){
                int row = wn*WN + j*16 + lrow;
                bfr[j] = *(const short8*)&lB[row*64 + (((kc*4+quad) ^ (row&7))<<3)];
            }
            #pragma unroll
            for (int i=0;i<MI;i++)
                #pragma unroll
                for (int j=0;j<NI;j++)
                    acc[i][j] = __builtin_amdgcn_mfma_f32_16x16x32_bf16(afr[i], bfr[j], acc[i][j], 0, 0, 0);
        }
    }

    // bias hoist: only NI distinct columns per thread
    float bcol[NI];
    #pragma unroll
    for (int j=0;j<NI;j++){
        int col = tile_n + wn*WN + j*16 + lrow;
        if constexpr (MODE == EPI_ATOMIC) { bcol[j] = 0.f; }
        else if constexpr (MODE == EPI_BF16) {
            bcol[j] = (col < Nst) ? b2f(((const bf16*)bias)[bias_off + col]) : 0.f;
        } else {
            bcol[j] = (col < Nst) ? ldw(bias, bias_off + col, isf) : 0.f;
        }
    }

    #pragma unroll
    for (int i=0;i<MI;i++) {
        #pragma unroll
        for (int j=0;j<NI;j++) {
            int col = tile_n + wn*WN + j*16 + lrow;
            if (col >= Nst) continue;
            int rb  = tile_m + wm*WM + i*16 + quad*4;
            #pragma unroll
            for (int r=0;r<4;r++) {
                int row = rb + r;
                if (row >= M) continue;
                float v = acc[i][j][r];
                if constexpr (MODE == EPI_BF16 || MODE == EPI_BF16R) {
                    C16[(long)row*ldc + col] = f2b(v + bcol[j]);
                } else if constexpr (MODE == EPI_F32) {
                    C32[(long)row*ldc + col] = v + bcol[j];
                } else if constexpr (MODE == EPI_GELU) {
                    C16[(long)row*ldc + col] = f2b(gelu_f(v + bcol[j]));
                } else { // EPI_ATOMIC
                    atomicAdd(&C32[(long)row*ldc + col], v);
                }
            }
        }
    }
}

// ---------------- flash attention ----------------
// Early-exit over KV tiles (bit-identical: masked tiles give exp()==0.0f).
// QBLK=64 (one 16-row strip per wave): LDS 48KB -> 3 blocks/CU
// (launch_bounds(256,3)), grid 9x256=2304 blocks for load balance.
// K/V double-buffered across the kt loop; XCD swizzle keeps the 9 q-tiles
// of one (b,h) on one XCD's L2.
__global__ __launch_bounds__(256,3) void flash_k(
    const bf16* __restrict__ qkv, const bf16* __restrict__ Vt,
    bf16* __restrict__ ctx, const int* __restrict__ slens)
{
    __shared__ __align__(16) bf16 lQ[64*64];
    __shared__ __align__(16) bf16 lK[2][64*64];
    __shared__ __align__(16) bf16 lV[2][64*64];
    __shared__ __align__(16) bf16 lP[64*64];
    const int nwg = gridDim.x * gridDim.z;
    const int flat = blockIdx.z * gridDim.x + blockIdx.x;
    const int swz = xcd_swizzle(flat, nwg);
    const int z = swz / gridDim.x, b = z>>3, h = z&7;
    const int qt = swz % gridDim.x;
    const int tid = threadIdx.x;
    const int w = tid>>6, lane = tid&63;
    const int quad = lane>>4, l15 = lane&15;
    int L = slens[b]; L = L<1?1:(L>S_N?S_N:L);
    const int lenT = L + T_N;
    const int nkt = (lenT + 63) >> 6;   // active KV tiles (wave-uniform)

    #pragma unroll
    for (int rr=0;rr<2;rr++){
        int ci = rr*256 + tid;
        int row = ci>>3, c8 = (ci&7) ^ (row&7);
        int gr = qt*64 + row; gr = gr < ST_N ? gr : ST_N-1;
        load_lds16(qkv + ((long)(b*ST_N+gr))*1536 + h*64 + c8*8, &lQ[ci*8]);
    }

    auto stage_K = [&](int buf, int kt){
        #pragma unroll
        for (int rr=0;rr<2;rr++){
            int ci = rr*256+tid;
            int row = ci>>3, c8 = (ci&7) ^ (row&7);
            int kr = kt*64+row; kr = kr < ST_N ? kr : ST_N-1;
            load_lds16(qkv + ((long)(b*ST_N+kr))*1536 + 512 + h*64 + c8*8, &lK[buf][ci*8]);
        }
    };
    auto stage_V = [&](int buf, int kt){
        #pragma unroll
        for (int rr=0;rr<2;rr++){
            int ci = rr*256+tid;
            int n = ci>>3, c8 = (ci&7) ^ (n&7);
            load_lds16(Vt + ((long)z*64+n)*STP_N + kt*64 + c8*8, &lV[buf][ci*8]);
        }
    };

    stage_K(0, 0);
    stage_V(0, 0);

    f32x4 zerov = {0.f,0.f,0.f,0.f};
    f32x4 O[4];
    float m_i[4], l_i[4];
    #pragma unroll
    for (int j=0;j<4;j++) O[j] = zerov;
    #pragma unroll
    for (int r=0;r<4;r++){ m_i[r]=-1e30f; l_i[r]=0.f; }

    const int qrow = w*16;   // wave's 16-row strip

    for (int kt=0; kt<nkt; kt++){
        const int cur = kt & 1;
        __syncthreads();                         // K[cur],V[cur] ready; lP reads done
        if (kt+1 < nkt) stage_K(cur^1, kt+1);    // overlaps QK + softmax

        f32x4 S[4];
        #pragma unroll
        for (int j=0;j<4;j++) S[j] = zerov;
        #pragma unroll
        for (int kc=0;kc<2;kc++){
            short8 aQ, bK[4];
            {
                int row = qrow + l15;
                aQ = *(const short8*)&lQ[row*64 + (((kc*4+quad) ^ (row&7))<<3)];
            }
            #pragma unroll
            for (int j=0;j<4;j++){
                int row = j*16+l15;
                bK[j] = *(const short8*)&lK[cur][row*64 + (((kc*4+quad) ^ (row&7))<<3)];
            }
            #pragma unroll
            for (int j=0;j<4;j++)
                S[j] = __builtin_amdgcn_mfma_f32_16x16x32_bf16(aQ, bK[j], S[j], 0,0,0);
        }

        #pragma unroll
        for (int r=0;r<4;r++){
            float mx = -1e30f;
            #pragma unroll
            for (int j=0;j<4;j++){
                int col = kt*64 + j*16 + l15;
                float s = S[j][r]*0.125f + (col < lenT ? 0.f : -10000.f);
                S[j][r] = s;
                mx = fmaxf(mx, s);
            }
            #pragma unroll
            for (int o=1;o<16;o<<=1) mx = fmaxf(mx, __shfl_xor(mx, o, 64));
            float mn = fmaxf(m_i[r], mx);
            float alpha = __expf(m_i[r] - mn);
            m_i[r] = mn;
            float sm = 0.f;
            #pragma unroll
            for (int j=0;j<4;j++){
                float pv = __expf(S[j][r] - mn);
                S[j][r] = pv;
                sm += pv;
            }
            #pragma unroll
            for (int o=1;o<16;o<<=1) sm += __shfl_xor(sm, o, 64);
            l_i[r] = l_i[r]*alpha + sm;
            #pragma unroll
            for (int j=0;j<4;j++) O[j][r] *= alpha;
        }

        #pragma unroll
        for (int j=0;j<4;j++)
            #pragma unroll
            for (int r=0;r<4;r++){
                int row = qrow + quad*4 + r;
                int col = j*16 + l15;
                lP[row*64 + (((col>>3) ^ (row&7))<<3) + (col&7)] = f2b(S[j][r]);
            }
        __syncthreads();                         // lP visible
        if (kt+1 < nkt) stage_V(cur^1, kt+1);    // overlaps PV

        #pragma unroll
        for (int kc=0;kc<2;kc++){
            short8 aP, bV[4];
            {
                int row = qrow + l15;
                aP = *(const short8*)&lP[row*64 + (((kc*4+quad) ^ (row&7))<<3)];
            }
            #pragma unroll
            for (int j=0;j<4;j++){
                int row = j*16+l15;
                bV[j] = *(const short8*)&lV[cur][row*64 + (((kc*4+quad) ^ (row&7))<<3)];
            }
            #pragma unroll
            for (int j=0;j<4;j++)
                O[j] = __builtin_amdgcn_mfma_f32_16x16x32_bf16(aP, bV[j], O[j], 0,0,0);
        }
    }

    #pragma unroll
    for (int r=0;r<4;r++){
        int row = qt*64 + qrow + quad*4 + r;
        if (row >= ST_N) continue;
        float inv_l = __builtin_amdgcn_rcpf(l_i[r]);
        #pragma unroll
        for (int j=0;j<4;j++)
            ctx[((long)(b*ST_N+row))*512 + h*64 + j*16 + l15] = f2b(O[j][r] * inv_l);
    }
}

// ---------------- residual + LN (fp32 state + bf16 shadow), bf16 tmp ----------------
__global__ __launch_bounds__(256) void ln_residual_k(
    const bf16* __restrict__ tmp, float* __restrict__ hf, bf16* __restrict__ hb,
    const void* __restrict__ g, const void* __restrict__ bb, long goff,
    void* __restrict__ outp, int is_final, const int* __restrict__ flagp)
{
    const int isf = *flagp;
    const int of32 = is_final && isf;
    long base = (long)blockIdx.x * 512;
    int t = threadIdx.x;
    float v0 = hf[base+t]     + b2f(tmp[base+t]);
    float v1 = hf[base+t+256] + b2f(tmp[base+t+256]);
    __shared__ float red[4];
    float mean = block_reduce_sum(v0+v1, red, t) * (1.f/512.f);
    float d0=v0-mean, d1=v1-mean;
    __syncthreads();
    float var = block_reduce_sum(d0*d0+d1*d1, red, t) * (1.f/512.f);
    float rstd = rsqrtf(var + 1e-12f);
    float o0 = d0*rstd*ldw(g,goff+t,isf) + ldw(bb,goff+t,isf);
    float o1 = d1*rstd*ldw(g,goff+t+256,isf) + ldw(bb,goff+t+256,isf);
    hf[base+t]=o0; hf[base+t+256]=o1;
    hb[base+t]=f2b(o0); hb[base+t+256]=f2b(o1);
    if (of32) {
        ((float*)outp)[base+t]=o0; ((float*)outp)[base+t+256]=o1;
    } else {
        ((bf16*)outp)[base+t]=f2b(o0); ((bf16*)outp)[base+t+256]=f2b(o1);
    }
}

extern "C" void kernel_launch(void* const* d_in, const int* in_sizes, int n_in,
                              void* d_out, int out_size, void* d_ws, size_t ws_size,
                              hipStream_t stream)
{
    (void)in_sizes; (void)n_in; (void)out_size; (void)ws_size;
    const int*  ids   = (const int*) d_in[0];
    const int*  slens = (const int*) d_in[1];
    const void* embed = d_in[2];
    const void* Wdec  = d_in[3];
    const void* bdec  = d_in[4];
    const void* mW1   = d_in[5];
    const void* mb1   = d_in[6];
    const void* mW2   = d_in[7];
    const void* mb2   = d_in[8];
    const void* mlg   = d_in[9];
    const void* mlb   = d_in[10];
    const void* Wq    = d_in[11];
    const void* bq    = d_in[12];
    const void* Wk    = d_in[13];
    const void* bk    = d_in[14];
    const void* Wv    = d_in[15];
    const void* bv    = d_in[16];
    const void* Wo    = d_in[17];
    const void* bo    = d_in[18];
    const void* l1g   = d_in[19];
    const void* l1b   = d_in[20];
    const void* Wi    = d_in[21];
    const void* bi    = d_in[22];
    const void* Wf    = d_in[23];
    const void* bfv   = d_in[24];
    const void* l2g   = d_in[25];
    const void* l2b   = d_in[26];

    char* p = (char*)d_ws;
    auto alloc = [&](size_t bytes)->void* {
        void* r = (void*)p; p += (bytes + 255) & ~(size_t)255; return r; };
    int*   flag  = (int*)  alloc(256);
    float* pmax  = (float*)alloc((size_t)T_N*WCH_N*4);
    float* psum  = (float*)alloc((size_t)T_N*WCH_N*4);
    float* tmf   = (float*)alloc((size_t)T_N*512*4);
    bf16*  tmb   = (bf16*) alloc((size_t)T_N*512*2);
    float* hmem  = (float*)alloc((size_t)64*1024*4);
    bf16*  hrel  = (bf16*) alloc((size_t)64*1024*2);
    float* fcout = (float*)alloc((size_t)64*512*4);
    float* hidf  = (float*)alloc((size_t)NTOK_N*512*4);
    bf16*  hidb  = (bf16*) alloc((size_t)NTOK_N*512*2);
    bf16*  qkvt  = (bf16*) alloc((size_t)NL_N*1536*512*2);
    bf16*  wot   = (bf16*) alloc((size_t)NL_N*512*512*2);
    bf16*  wit   = (bf16*) alloc((size_t)NL_N*2048*512*2);
    bf16*  wft   = (bf16*) alloc((size_t)NL_N*512*2048*2);
    bf16*  bqkv  = (bf16*) alloc((size_t)NL_N*1536*2);
    // R1 union (time-disjoint): prelude [wdb 3.84M | W1t 61.5M | W2t 1M] <-> [qkv 55.25M] <-> [ffb 73.66M]
    char*  R1    = (char*) alloc((size_t)NTOK_N*2048*2);
    bf16*  wdb   = (bf16*)R1;
    bf16*  W1t   = (bf16*)(R1 + (size_t)64*VBP_N*2);
    bf16*  W2t   = (bf16*)(R1 + (size_t)64*VBP_N*2 + (size_t)1024*VBP_N*2);
    bf16*  qkv   = (bf16*)R1;
    bf16*  ffb   = (bf16*)R1;
    // RU2: ctx (18.42M) + [Vt 18.87M <-> tmp16 18.42M]
    bf16*  ctx   = (bf16*) alloc((size_t)NTOK_N*512*2);
    char*  RU2   = (char*) alloc((size_t)NTOK_N*512*4);
    bf16*  Vt    = (bf16*)RU2;
    bf16*  tmp16 = (bf16*)RU2;
    // total ~= 210 MB

    detect_k<<<1,256,0,stream>>>((const unsigned int*)embed, flag);

    // topic memory: parallel softmax -> FC1 (MFMA, K-split atomic) -> relu -> FC2 (MFMA) -> LN
    zero_u32_k<<<((64L*VBP_N/2)+255)/256,256,0,stream>>>((unsigned int*)wdb, 64L*VBP_N/2);
    zero_u32_k<<<((64L*1024)+255)/256,256,0,stream>>>((unsigned int*)hmem, 64L*1024);
    wd_partmax_k<<<dim3(WCH_N,T_N),256,0,stream>>>(Wdec,bdec,pmax,flag);
    wd_partsum_k<<<dim3(WCH_N,T_N),256,0,stream>>>(Wdec,bdec,pmax,psum,flag);
    wd_write_k  <<<dim3(WCH_N,T_N),256,0,stream>>>(Wdec,bdec,pmax,psum,wdb,flag);
    transpose_k<<<dim3(32,VBP_N/32,1),256,0,stream>>>(mW1, W1t, VBP_N, 1024, 0L, 0L, VB_N, flag);
    transpose_k<<<dim3(16,32,1),256,0,stream>>>(mW2, W2t, 1024, 512, 0L, 0L, 1024, flag);
    gemm_k<64,128,EPI_ATOMIC><<<dim3(8,1,32),256,0,stream>>>(
        wdb, W1t, hmem, nullptr, 0,
        64, 1024, VBP_N, VBP_N, VBP_N, 1024, 1024, 960, flag);
    relu_bias_k<<<64,256,0,stream>>>(hmem, mb1, hrel, flag);
    gemm_k<64,128,EPI_F32><<<dim3(4,1,1),256,0,stream>>>(
        hrel, W2t, fcout, mb2, 0,
        64, 512, 1024, 1024, 1024, 512, 512, 0, flag);
    ln_topic_k<<<T_N,256,0,stream>>>(fcout, mlg, mlb, tmf, tmb, flag);
    embed_insert_k<<<dim3(ST_N,B_N),256,0,stream>>>(ids, slens, embed, tmf, tmb, hidf, hidb, flag);

    // weight prep (canonical bf16, [N][K] layouts)
    transpose_k<<<dim3(16,16,NL_N),256,0,stream>>>(Wq, qkvt,          512, 512, 262144L, 786432L, 512, flag);
    transpose_k<<<dim3(16,16,NL_N),256,0,stream>>>(Wk, qkvt+262144,   512, 512, 262144L, 786432L, 512, flag);
    transpose_k<<<dim3(16,16,NL_N),256,0,stream>>>(Wv, qkvt+524288,   512, 512, 262144L, 786432L, 512, flag);
    transpose_k<<<dim3(16,16,NL_N),256,0,stream>>>(Wo, wot,           512, 512, 262144L, 262144L, 512, flag);
    transpose_k<<<dim3(64,16,NL_N),256,0,stream>>>(Wi, wit,           512, 2048, 1048576L, 1048576L, 512, flag);
    transpose_k<<<dim3(16,64,NL_N),256,0,stream>>>(Wf, wft,           2048, 512, 1048576L, 1048576L, 2048, flag);
    concat_bias_k<<<(NL_N*1536+255)/256,256,0,stream>>>(bq,bk,bv,bqkv,flag);

    for (int l=0;l<NL_N;l++) {
        gemm_k<128,128,EPI_BF16><<<dim3(12,141,1),256,0,stream>>>(
            hidb, qkvt + (size_t)l*786432, qkv, bqkv, (long)l*1536,
            NTOK_N, 1536, 512, 512, 512, 1536, 1536, 0, flag);
        transpose_v_k<<<dim3(18,1,256),256,0,stream>>>(qkv, Vt, slens);
        flash_k<<<dim3(9,1,256),256,0,stream>>>(qkv, Vt, ctx, slens);
        gemm_k<128,128,EPI_BF16R><<<dim3(4,141,1),256,0,stream>>>(
            ctx, wot + (size_t)l*262144, tmp16, bo, (long)l*512,
            NTOK_N, 512, 512, 512, 512, 512, 512, 0, flag);
        ln_residual_k<<<NTOK_N,256,0,stream>>>(tmp16, hidf, hidb, l1g, l1b, (long)l*512,
                                               hidb, 0, flag);
        gemm_k<128,128,EPI_GELU><<<dim3(16,141,1),256,0,stream>>>(
            hidb, wit + (size_t)l*1048576, ffb, bi, (long)l*2048,
            NTOK_N, 2048, 512, 512, 512, 2048, 2048, 0, flag);
        gemm_k<128,128,EPI_BF16R><<<dim3(4,141,1),256,0,stream>>>(
            ffb, wft + (size_t)l*1048576, tmp16, bfv, (long)l*512,
            NTOK_N, 512, 2048, 2048, 2048, 512, 512, 0, flag);
        ln_residual_k<<<NTOK_N,256,0,stream>>>(tmp16, hidf, hidb, l2g, l2b, (long)l*512,
                                               (l == NL_N-1) ? d_out : (void*)hidb,
                                               (l == NL_N-1) ? 1 : 0, flag);
    }
}